// Round 11
// baseline (348.459 us; speedup 1.0000x reference)
//
#include <hip/hip_runtime.h>
#include <hip/hip_bf16.h>
#include <stdint.h>

typedef __attribute__((ext_vector_type(4))) float f4;
typedef __attribute__((ext_vector_type(2))) float f2;
typedef __attribute__((ext_vector_type(2))) int i2;
typedef __attribute__((ext_vector_type(8))) unsigned short us8;
typedef __attribute__((ext_vector_type(4))) unsigned short us4;
typedef __attribute__((ext_vector_type(2))) unsigned short us2;
typedef __attribute__((ext_vector_type(8))) short s8b;    // MFMA A/B frag (8 bf16)
typedef __attribute__((ext_vector_type(4))) float f32x4;  // MFMA C/D frag

#define CW_SHIFT 7            // 128 cols per bucket
#define CH 8192               // edges per block in bin phases

__device__ __forceinline__ float bf2f(unsigned short u) {
  union { unsigned int i; float f; } t; t.i = ((unsigned int)u) << 16; return t.f;
}
__device__ __forceinline__ unsigned short f2bf(float f) {
  union { float f; unsigned int i; } t; t.f = f;
  unsigned int u = t.i;
  return (unsigned short)((u + 0x7FFFu + ((u >> 16) & 1u)) >> 16);
}
__device__ __forceinline__ float cvtload(const void* p, int i, int f16) {
  return f16 ? bf2f(((const unsigned short*)p)[i]) : ((const float*)p)[i];
}

// ---- dtype detection ----
__global__ void detect_kernel(const unsigned int* __restrict__ xb,
                              const unsigned int* __restrict__ ib,
                              int* __restrict__ flags) {
  if (threadIdx.x == 0) {
    int cnt = 0;
    for (int i = 0; i < 256; ++i) {
      unsigned int e = (xb[i] >> 7) & 0xffu;
      if (e >= 110u && e <= 135u) ++cnt;
    }
    flags[0] = (cnt >= 180) ? 1 : 0;
    int zc = 0;
    for (int i = 0; i < 128; ++i) if (ib[2 * i + 1] == 0u) ++zc;
    flags[1] = (zc >= 120) ? 1 : 0;
  }
}

// ---- fused parameter convert: wM, fc_w^T, fc_b, conv_w^T, conv_b ----
__global__ void cvt_params(const void* __restrict__ wM, const void* __restrict__ fcw,
                           const void* __restrict__ fcb, const void* __restrict__ cw,
                           const void* __restrict__ cb,
                           float* __restrict__ WMf, unsigned short* __restrict__ FCWT,
                           float* __restrict__ FCB, unsigned short* __restrict__ CWT,
                           float* __restrict__ CBf,
                           int E, int L, const int* __restrict__ flags) {
  const int IN_DIM = 256, D = 128;
  int i = blockIdx.x * 256 + threadIdx.x;
  const int f16 = flags[0];
  if (i < E) { WMf[i] = cvtload(wM, i, f16); return; }
  i -= E;
  if (i < IN_DIM * D) {
    int c = i >> 8, k = i & 255;
    FCWT[i] = f2bf(cvtload(fcw, k * D + c, f16));
    return;
  }
  i -= IN_DIM * D;
  if (i < D) { FCB[i] = cvtload(fcb, i, f16); return; }
  i -= D;
  if (i < L * D * D) {
    int l = i >> 14, rem = i & 16383;
    int c = rem >> 7, k = rem & 127;
    CWT[i] = f2bf(cvtload(cw, l * D * D + k * D + c, f16));
    return;
  }
  i -= L * D * D;
  if (i < L * D) CBf[i] = cvtload(cb, i, f16);
}

// ---- phase 1: per-(block,bucket) histograms only ----
__global__ __launch_bounds__(256) void bin_count(
    const void* __restrict__ hei, int M, int* __restrict__ cntAB,
    int nbE, int nbN, int nblk, const int* __restrict__ flags) {
  __shared__ int hA[512];
  __shared__ int hB[512];
  const int tid = threadIdx.x, blk = blockIdx.x;
  for (int b = tid; b < 512; b += 256) { hA[b] = 0; hB[b] = 0; }
  __syncthreads();
  const int i64 = flags[1];
  const int mEnd = min(M, (blk + 1) * CH);
  for (int m = blk * CH + tid; m < mEnd; m += 256) {
    int r, c;
    if (i64) {
      r = (int)((const long long*)hei)[m];
      c = (int)((const long long*)hei)[M + m];
    } else {
      r = ((const int*)hei)[m];
      c = ((const int*)hei)[M + m];
    }
    atomicAdd(&hA[c >> CW_SHIFT], 1);
    atomicAdd(&hB[r >> CW_SHIFT], 1);
  }
  __syncthreads();
  for (int b = tid; b < nbE; b += 256) cntAB[b * nblk + blk] = hA[b];
  for (int b = tid; b < nbN; b += 256) cntAB[(nbE + b) * nblk + blk] = hB[b];
}

// ---- scanA: per-bucket exclusive scan over nblk block counts (both families) ----
__global__ __launch_bounds__(512) void scanA(int* __restrict__ cnt,
                                             int* __restrict__ btot, int nblk) {
  __shared__ int sc[512];
  const int tid = threadIdx.x, b = blockIdx.x;
  int v = (tid < nblk) ? cnt[b * nblk + tid] : 0;
  sc[tid] = v;
  __syncthreads();
  for (int s = 1; s < 512; s <<= 1) {
    int t = (tid >= s) ? sc[tid - s] : 0;
    __syncthreads();
    sc[tid] += t;
    __syncthreads();
  }
  if (tid < nblk) cnt[b * nblk + tid] = sc[tid] - v;
  if (tid == 511) btot[b] = sc[511];
}

// ---- scanB: 2 blocks; block0 scans A-family totals, block1 B-family ----
__global__ __launch_bounds__(512) void scanB(const int* __restrict__ btot,
                                             int* __restrict__ bbaseA,
                                             int* __restrict__ bbaseB,
                                             int nbE, int nbN) {
  __shared__ int sc[512];
  const int tid = threadIdx.x;
  const int nb = blockIdx.x ? nbN : nbE;
  const int* src = blockIdx.x ? (btot + nbE) : btot;
  int* dst = blockIdx.x ? bbaseB : bbaseA;
  int v = (tid < nb) ? src[tid] : 0;
  sc[tid] = v;
  __syncthreads();
  for (int s = 1; s < 512; s <<= 1) {
    int t = (tid >= s) ? sc[tid - s] : 0;
    __syncthreads();
    sc[tid] += t;
    __syncthreads();
  }
  if (tid < nb) dst[tid] = sc[tid] - v;
  if (tid == 511) dst[nb] = sc[511];
}

// ---- phase 2: decode hei/ew inline + scatter packed 8B entries ----
// PAY entry: p0 = src | (key7 << 20), p1 = ew bits (full fp32)
__global__ __launch_bounds__(256) void binscatter(
    const void* __restrict__ hei, const void* __restrict__ ew, int M,
    const int* __restrict__ cntAB,
    const int* __restrict__ bbaseA, const int* __restrict__ bbaseB,
    i2* __restrict__ PAYA, i2* __restrict__ PAYB,
    int nbE, int nbN, int nblk, const int* __restrict__ flags) {
  __shared__ int baseA[512];
  __shared__ int baseB[512];
  const int tid = threadIdx.x, blk = blockIdx.x;
  for (int b = tid; b < nbE; b += 256) baseA[b] = bbaseA[b] + cntAB[b * nblk + blk];
  for (int b = tid; b < nbN; b += 256) baseB[b] = bbaseB[b] + cntAB[(nbE + b) * nblk + blk];
  __syncthreads();
  const int i64 = flags[1], f16 = flags[0];
  const int mEnd = min(M, (blk + 1) * CH);
  for (int m = blk * CH + tid; m < mEnd; m += 256) {
    int r, c;
    if (i64) {
      r = (int)((const long long*)hei)[m];
      c = (int)((const long long*)hei)[M + m];
    } else {
      r = ((const int*)hei)[m];
      c = ((const int*)hei)[M + m];
    }
    int e = __float_as_int(f16 ? bf2f(((const unsigned short*)ew)[m])
                               : ((const float*)ew)[m]);
    int pA = atomicAdd(&baseA[c >> CW_SHIFT], 1);
    i2 ea; ea[0] = r | ((c & 127) << 20); ea[1] = e;
    PAYA[pA] = ea;
    int pB = atomicAdd(&baseB[r >> CW_SHIFT], 1);
    i2 eb; eb[0] = c | ((r & 127) << 20); eb[1] = e;
    PAYB[pB] = eb;
  }
}

// ---- phase 3 (combined): per-bucket finalize -> CSR entries + offsets + scales ----
__global__ __launch_bounds__(256) void finalize3(
    const i2* __restrict__ PAYA, const int* __restrict__ bbaseA,
    i2* __restrict__ ENTA, int* __restrict__ offE, int E,
    const i2* __restrict__ PAYB, const int* __restrict__ bbaseB,
    i2* __restrict__ ENTB, int* __restrict__ offN, int Nn,
    const float* __restrict__ WMf, float* __restrict__ SCE,
    float* __restrict__ ND, int nbE) {
  __shared__ int cnt[128];
  __shared__ int sc[128];
  __shared__ int cur[128];
  __shared__ float fsum[128];
  int b = blockIdx.x;
  const i2* PAY; const int* bbase; i2* ENT; int* off;
  int nseg, modeB; float* outScale;
  if (b < nbE) {
    PAY = PAYA; bbase = bbaseA; ENT = ENTA; off = offE;
    nseg = E; modeB = 0; outScale = SCE;
  } else {
    b -= nbE;
    PAY = PAYB; bbase = bbaseB; ENT = ENTB; off = offN;
    nseg = Nn; modeB = 1; outScale = ND;
  }
  const int tid = threadIdx.x;
  const int bs = bbase[b], be = bbase[b + 1];
  const int cb = b << CW_SHIFT;
  const int cw = min(128, nseg - cb);
  if (tid < 128) { cnt[tid] = 0; fsum[tid] = 0.f; }
  __syncthreads();
  for (int k = bs + tid; k < be; k += 256)
    atomicAdd(&cnt[(PAY[k][0] >> 20) & 127], 1);
  __syncthreads();
  if (tid < 128) sc[tid] = cnt[tid];
  __syncthreads();
  for (int s = 1; s < 128; s <<= 1) {
    int t = (tid < 128 && tid >= s) ? sc[tid - s] : 0;
    __syncthreads();
    if (tid < 128) sc[tid] += t;
    __syncthreads();
  }
  if (tid < 128) {
    int start = bs + sc[tid] - cnt[tid];
    cur[tid] = start;
    if (tid < cw) off[cb + tid] = start;
  }
  if (tid == 0 && b == ((nseg + 127) >> CW_SHIFT) - 1) off[nseg] = be;
  __syncthreads();
  for (int k = bs + tid; k < be; k += 256) {
    i2 p = PAY[k];
    int key = (p[0] >> 20) & 127;
    int src = p[0] & 0xFFFFF;
    int pos = atomicAdd(&cur[key], 1);
    i2 outp; outp[0] = src; outp[1] = p[1];
    ENT[pos] = outp;
    float add = modeB ? WMf[src] : __int_as_float(p[1]);
    atomicAdd(&fsum[key], add);
  }
  __syncthreads();
  if (tid < cw) {
    float s = fsum[tid] + 1e-8f;
    outScale[cb + tid] = modeB ? rsqrtf(s) : (WMf[cb + tid] / s);
  }
}

// ---- MFMA GEMM v3: LDS-staged weights + fully hoisted A loads ----
template<int KS>
__global__ __launch_bounds__(256) void gemm_mfma3(
    const void* __restrict__ Aptr, const unsigned short* __restrict__ Wt,
    const float* __restrict__ bias, unsigned short* __restrict__ out,
    int Nrows, const int* __restrict__ flags, int relu,
    const float* __restrict__ rowScale) {
  constexpr int K = KS * 32;
  constexpr int KC = K / 8;
  extern __shared__ unsigned short Bs[];
  const int tid = threadIdx.x;
  const int wv = tid >> 6, ln = tid & 63;
  const int lr = ln & 15;
  const int lk = (ln >> 4) << 3;
  const int rowBase = blockIdx.x * 128 + wv * 32;
  const int aF32 = flags ? (flags[0] ? 0 : 1) : 0;

  int ar[2];
#pragma unroll
  for (int t = 0; t < 2; ++t) {
    int r = rowBase + t * 16 + lr;
    ar[t] = (r < Nrows) ? r : (Nrows - 1);
  }

  s8b aR[2][KS];
  if (!aF32) {
#pragma unroll
    for (int t = 0; t < 2; ++t)
#pragma unroll
      for (int ks = 0; ks < KS; ++ks)
        aR[t][ks] = *reinterpret_cast<const s8b*>(
            (const unsigned short*)Aptr + (size_t)ar[t] * K + ks * 32 + lk);
  } else {
#pragma unroll
    for (int t = 0; t < 2; ++t)
#pragma unroll
      for (int ks = 0; ks < KS; ++ks) {
        const float* ap = (const float*)Aptr + (size_t)ar[t] * K + ks * 32 + lk;
        f4 u0 = *reinterpret_cast<const f4*>(ap);
        f4 u1 = *reinterpret_cast<const f4*>(ap + 4);
#pragma unroll
        for (int j = 0; j < 4; ++j) {
          aR[t][ks][j]     = (short)f2bf(u0[j]);
          aR[t][ks][4 + j] = (short)f2bf(u1[j]);
        }
      }
  }

#pragma unroll
  for (int it = 0; it < (128 * KC + 255) / 256; ++it) {
    int ch = it * 256 + tid;
    if (ch < 128 * KC) {
      int row = ch / KC, kc = (ch % KC) << 3;
      us8 v = *reinterpret_cast<const us8*>(Wt + (size_t)row * K + kc);
      int byte = ((row * K + kc) << 1) ^ ((row & 7) << 4);
      *reinterpret_cast<us8*>((char*)Bs + byte) = v;
    }
  }
  __syncthreads();

  f32x4 acc[2][8];
#pragma unroll
  for (int t = 0; t < 2; ++t)
#pragma unroll
    for (int n = 0; n < 8; ++n) acc[t][n] = (f32x4)0.f;

#pragma unroll
  for (int ks = 0; ks < KS; ++ks) {
#pragma unroll
    for (int n = 0; n < 8; ++n) {
      const int brow = n * 16 + lr;
      int byte = ((brow * K + ks * 32 + lk) << 1) ^ ((brow & 7) << 4);
      s8b b = *reinterpret_cast<const s8b*>((const char*)Bs + byte);
      acc[0][n] = __builtin_amdgcn_mfma_f32_16x16x32_bf16(aR[0][ks], b, acc[0][n], 0, 0, 0);
      acc[1][n] = __builtin_amdgcn_mfma_f32_16x16x32_bf16(aR[1][ks], b, acc[1][n], 0, 0, 0);
    }
  }

#pragma unroll
  for (int t = 0; t < 2; ++t) {
    const int orow0 = rowBase + t * 16 + ((ln >> 4) << 2);
#pragma unroll
    for (int n = 0; n < 8; ++n) {
      const int col = n * 16 + lr;
      const float bv = bias[col];
#pragma unroll
      for (int r = 0; r < 4; ++r) {
        int row = orow0 + r;
        if (row >= Nrows) continue;
        float s = acc[t][n][r] + bv;
        if (relu) s = fmaxf(s, 0.f);
        if (rowScale) s *= rowScale[row];
        out[(size_t)row * 128 + col] = f2bf(s);
      }
    }
  }
}

// ---- gather v4: 2 segments/wave, 32 lanes * us4 (8B), 8-deep unroll ----
__global__ __launch_bounds__(256) void gather_edge3(
    const int* __restrict__ off, const i2* __restrict__ ENT,
    const float* __restrict__ sc_e, const unsigned short* __restrict__ X,
    unsigned short* __restrict__ out, int nseg) {
  int seg = blockIdx.x * 8 + (threadIdx.x >> 5);
  if (seg >= nseg) return;
  int d = (threadIdx.x & 31) << 2;
  int k0 = off[seg], k1 = off[seg + 1];
  float a0 = 0.f, a1 = 0.f, a2 = 0.f, a3 = 0.f;
  int k = k0;
  for (; k + 8 <= k1; k += 8) {
    i2 e[8]; us4 v[8];
#pragma unroll
    for (int j = 0; j < 8; ++j) e[j] = ENT[k + j];
#pragma unroll
    for (int j = 0; j < 8; ++j)
      v[j] = *reinterpret_cast<const us4*>(X + (size_t)e[j][0] * 128 + d);
#pragma unroll
    for (int j = 0; j < 8; ++j) {
      float c = __int_as_float(e[j][1]);
      a0 += c * bf2f(v[j][0]); a1 += c * bf2f(v[j][1]);
      a2 += c * bf2f(v[j][2]); a3 += c * bf2f(v[j][3]);
    }
  }
  for (; k < k1; ++k) {
    i2 e = ENT[k];
    us4 v = *reinterpret_cast<const us4*>(X + (size_t)e[0] * 128 + d);
    float c = __int_as_float(e[1]);
    a0 += c * bf2f(v[0]); a1 += c * bf2f(v[1]); a2 += c * bf2f(v[2]); a3 += c * bf2f(v[3]);
  }
  float sc = sc_e[seg];
  us4 o;
  o[0] = f2bf(sc * a0); o[1] = f2bf(sc * a1); o[2] = f2bf(sc * a2); o[3] = f2bf(sc * a3);
  *reinterpret_cast<us4*>(out + (size_t)seg * 128 + d) = o;
}

__global__ __launch_bounds__(256) void gather_node3(
    const int* __restrict__ off, const i2* __restrict__ ENT,
    const float* __restrict__ nd, const unsigned short* __restrict__ HF,
    const unsigned short* __restrict__ H, void* __restrict__ out,
    int nseg, int outF32) {
  int seg = blockIdx.x * 8 + (threadIdx.x >> 5);
  if (seg >= nseg) return;
  int d = (threadIdx.x & 31) << 2;
  int k0 = off[seg], k1 = off[seg + 1];
  float a0 = 0.f, a1 = 0.f, a2 = 0.f, a3 = 0.f;
  int k = k0;
  for (; k + 8 <= k1; k += 8) {
    i2 e[8]; us4 v[8];
#pragma unroll
    for (int j = 0; j < 8; ++j) e[j] = ENT[k + j];
#pragma unroll
    for (int j = 0; j < 8; ++j)
      v[j] = *reinterpret_cast<const us4*>(HF + (size_t)e[j][0] * 128 + d);
#pragma unroll
    for (int j = 0; j < 8; ++j) {
      float c = __int_as_float(e[j][1]);
      a0 += c * bf2f(v[j][0]); a1 += c * bf2f(v[j][1]);
      a2 += c * bf2f(v[j][2]); a3 += c * bf2f(v[j][3]);
    }
  }
  for (; k < k1; ++k) {
    i2 e = ENT[k];
    us4 v = *reinterpret_cast<const us4*>(HF + (size_t)e[0] * 128 + d);
    float c = __int_as_float(e[1]);
    a0 += c * bf2f(v[0]); a1 += c * bf2f(v[1]); a2 += c * bf2f(v[2]); a3 += c * bf2f(v[3]);
  }
  float s = nd[seg];
  us4 h = *reinterpret_cast<const us4*>(H + (size_t)seg * 128 + d);
  float r0 = fmaxf(bf2f(h[0]) + s * a0, 0.f);
  float r1 = fmaxf(bf2f(h[1]) + s * a1, 0.f);
  float r2 = fmaxf(bf2f(h[2]) + s * a2, 0.f);
  float r3 = fmaxf(bf2f(h[3]) + s * a3, 0.f);
  if (outF32) {
    f4 o; o[0] = r0; o[1] = r1; o[2] = r2; o[3] = r3;
    *reinterpret_cast<f4*>((float*)out + (size_t)seg * 128 + d) = o;
  } else {
    us4 o; o[0] = f2bf(r0); o[1] = f2bf(r1); o[2] = f2bf(r2); o[3] = f2bf(r3);
    *reinterpret_cast<us4*>((unsigned short*)out + (size_t)seg * 128 + d) = o;
  }
}

extern "C" void kernel_launch(void* const* d_in, const int* in_sizes, int n_in,
                              void* d_out, int out_size, void* d_ws, size_t ws_size,
                              hipStream_t stream) {
  const void* x   = d_in[0];
  const void* hei = d_in[1];
  const void* wM  = d_in[2];
  const void* ew  = d_in[3];
  const void* fcw = d_in[4];
  const void* fcb = d_in[5];
  const void* cw  = d_in[6];
  const void* cb  = d_in[7];

  const int IN_DIM = 256, D = 128;
  const int N = in_sizes[0] / IN_DIM;
  const int M = in_sizes[1] / 2;
  const int E = in_sizes[2];
  const int L = in_sizes[6] / (D * D);

  const int nbE = (E + 127) >> CW_SHIFT;
  const int nbN = (N + 127) >> CW_SHIFT;
  const int nbT = nbE + nbN;
  const int nblk = (M + CH - 1) / CH;

  float* w = (float*)d_ws;
  size_t o = 0;
  auto alloc = [&](size_t n) { float* p = w + o; o += (n + 3) & ~(size_t)3; return p; };

  // R region: XT+HF later; packed PAY bin arrays earlier (disjoint in time)
  float* R = alloc((size_t)(N + E) * D / 2);
  unsigned short* XT = (unsigned short*)R;
  unsigned short* HF = XT + (size_t)N * D;
  i2*  PAYA = (i2*)R;
  i2*  PAYB = PAYA + M;

  unsigned short* H  = (unsigned short*)alloc((size_t)N * D / 2);
  i2*    ENTA = (i2*)alloc((size_t)M * 2);
  i2*    ENTB = (i2*)alloc((size_t)M * 2);
  int*   cntAB = (int*)alloc((size_t)nbT * nblk);
  int*   btotAB = (int*)alloc(nbT + 2);
  int*   bbaseA = (int*)alloc(nbE + 2);
  int*   bbaseB = (int*)alloc(nbN + 2);
  float* ND   = alloc(N);
  float* SCE  = alloc(E);
  int*   offE = (int*)alloc(E + 1);
  int*   offN = (int*)alloc(N + 1);
  float* WMf  = alloc(E);
  unsigned short* FCWT = (unsigned short*)alloc((size_t)IN_DIM * D / 2);
  float* FCB  = alloc(D);
  unsigned short* CWT = (unsigned short*)alloc((size_t)L * D * D / 2);
  float* CBf  = alloc((size_t)L * D);
  int*   FLAGS = (int*)alloc(16);

  detect_kernel<<<1, 64, 0, stream>>>((const unsigned int*)x, (const unsigned int*)hei, FLAGS);

  bin_count<<<nblk, 256, 0, stream>>>(hei, M, cntAB, nbE, nbN, nblk, FLAGS);
  {
    int ntot = E + IN_DIM * D + D + L * D * D + L * D;
    cvt_params<<<(ntot + 255) / 256, 256, 0, stream>>>(wM, fcw, fcb, cw, cb,
                                                       WMf, FCWT, FCB, CWT, CBf,
                                                       E, L, FLAGS);
  }

  scanA<<<nbT, 512, 0, stream>>>(cntAB, btotAB, nblk);
  scanB<<<2, 512, 0, stream>>>(btotAB, bbaseA, bbaseB, nbE, nbN);

  binscatter<<<nblk, 256, 0, stream>>>(hei, ew, M, cntAB, bbaseA, bbaseB,
                                       PAYA, PAYB, nbE, nbN, nblk, FLAGS);

  finalize3<<<nbT, 256, 0, stream>>>(PAYA, bbaseA, ENTA, offE, E,
                                     PAYB, bbaseB, ENTB, offN, N,
                                     WMf, SCE, ND, nbE);

  // h0 = relu(x @ fc_w + fc_b)
  gemm_mfma3<8><<<(N + 127) / 128, 256, 128 * 256 * 2, stream>>>(
      x, FCWT, FCB, H, N, FLAGS, 1, nullptr);

  int segBlkE = (E + 7) / 8, segBlkN = (N + 7) / 8;
  for (int l = 0; l < L; ++l) {
    // xt' = nd[r] * (h @ conv_w[l] + conv_b[l])
    gemm_mfma3<4><<<(N + 127) / 128, 256, 128 * 128 * 2, stream>>>(
        H, CWT + (size_t)l * D * D, CBf + (size_t)l * D, XT, N,
        (const int*)nullptr, 0, ND);
    gather_edge3<<<segBlkE, 256, 0, stream>>>(offE, ENTA, SCE, XT, HF, E);
    gather_node3<<<segBlkN, 256, 0, stream>>>(
        offN, ENTB, ND, HF, H,
        (l == L - 1) ? d_out : (void*)H, N, (l == L - 1) ? 1 : 0);
  }
}

// Round 12
// 321.843 us; speedup vs baseline: 1.0827x; 1.0827x over previous
//
#include <hip/hip_runtime.h>
#include <hip/hip_bf16.h>
#include <stdint.h>

typedef __attribute__((ext_vector_type(4))) float f4;
typedef __attribute__((ext_vector_type(2))) float f2;
typedef __attribute__((ext_vector_type(2))) int i2;
typedef __attribute__((ext_vector_type(8))) unsigned short us8;
typedef __attribute__((ext_vector_type(4))) unsigned short us4;
typedef __attribute__((ext_vector_type(2))) unsigned short us2;
typedef __attribute__((ext_vector_type(8))) short s8b;    // MFMA A/B frag (8 bf16)
typedef __attribute__((ext_vector_type(4))) float f32x4;  // MFMA C/D frag

#define CW_SHIFT 7            // 128 cols per bucket
#define CH 2048               // edges per block in bin phases (313 blocks: occupancy > amplification)

__device__ __forceinline__ float bf2f(unsigned short u) {
  union { unsigned int i; float f; } t; t.i = ((unsigned int)u) << 16; return t.f;
}
__device__ __forceinline__ unsigned short f2bf(float f) {
  union { float f; unsigned int i; } t; t.f = f;
  unsigned int u = t.i;
  return (unsigned short)((u + 0x7FFFu + ((u >> 16) & 1u)) >> 16);
}
__device__ __forceinline__ float cvtload(const void* p, int i, int f16) {
  return f16 ? bf2f(((const unsigned short*)p)[i]) : ((const float*)p)[i];
}

// ---- dtype detection ----
__global__ void detect_kernel(const unsigned int* __restrict__ xb,
                              const unsigned int* __restrict__ ib,
                              int* __restrict__ flags) {
  if (threadIdx.x == 0) {
    int cnt = 0;
    for (int i = 0; i < 256; ++i) {
      unsigned int e = (xb[i] >> 7) & 0xffu;
      if (e >= 110u && e <= 135u) ++cnt;
    }
    flags[0] = (cnt >= 180) ? 1 : 0;
    int zc = 0;
    for (int i = 0; i < 128; ++i) if (ib[2 * i + 1] == 0u) ++zc;
    flags[1] = (zc >= 120) ? 1 : 0;
  }
}

// ---- fused parameter convert: wM, fc_w^T, fc_b, conv_w^T, conv_b ----
__global__ void cvt_params(const void* __restrict__ wM, const void* __restrict__ fcw,
                           const void* __restrict__ fcb, const void* __restrict__ cw,
                           const void* __restrict__ cb,
                           float* __restrict__ WMf, unsigned short* __restrict__ FCWT,
                           float* __restrict__ FCB, unsigned short* __restrict__ CWT,
                           float* __restrict__ CBf,
                           int E, int L, const int* __restrict__ flags) {
  const int IN_DIM = 256, D = 128;
  int i = blockIdx.x * 256 + threadIdx.x;
  const int f16 = flags[0];
  if (i < E) { WMf[i] = cvtload(wM, i, f16); return; }
  i -= E;
  if (i < IN_DIM * D) {
    int c = i >> 8, k = i & 255;
    FCWT[i] = f2bf(cvtload(fcw, k * D + c, f16));
    return;
  }
  i -= IN_DIM * D;
  if (i < D) { FCB[i] = cvtload(fcb, i, f16); return; }
  i -= D;
  if (i < L * D * D) {
    int l = i >> 14, rem = i & 16383;
    int c = rem >> 7, k = rem & 127;
    CWT[i] = f2bf(cvtload(cw, l * D * D + k * D + c, f16));
    return;
  }
  i -= L * D * D;
  if (i < L * D) CBf[i] = cvtload(cb, i, f16);
}

// ---- phase 1: per-(block,bucket) histograms only ----
__global__ __launch_bounds__(256) void bin_count(
    const void* __restrict__ hei, int M, int* __restrict__ cntAB,
    int nbE, int nbN, int nblk, const int* __restrict__ flags) {
  __shared__ int hA[512];
  __shared__ int hB[512];
  const int tid = threadIdx.x, blk = blockIdx.x;
  for (int b = tid; b < 512; b += 256) { hA[b] = 0; hB[b] = 0; }
  __syncthreads();
  const int i64 = flags[1];
  const int mEnd = min(M, (blk + 1) * CH);
  for (int m = blk * CH + tid; m < mEnd; m += 256) {
    int r, c;
    if (i64) {
      r = (int)((const long long*)hei)[m];
      c = (int)((const long long*)hei)[M + m];
    } else {
      r = ((const int*)hei)[m];
      c = ((const int*)hei)[M + m];
    }
    atomicAdd(&hA[c >> CW_SHIFT], 1);
    atomicAdd(&hB[r >> CW_SHIFT], 1);
  }
  __syncthreads();
  for (int b = tid; b < nbE; b += 256) cntAB[b * nblk + blk] = hA[b];
  for (int b = tid; b < nbN; b += 256) cntAB[(nbE + b) * nblk + blk] = hB[b];
}

// ---- scanA: per-bucket exclusive scan over nblk block counts (both families) ----
__global__ __launch_bounds__(512) void scanA(int* __restrict__ cnt,
                                             int* __restrict__ btot, int nblk) {
  __shared__ int sc[512];
  const int tid = threadIdx.x, b = blockIdx.x;
  int v = (tid < nblk) ? cnt[b * nblk + tid] : 0;
  sc[tid] = v;
  __syncthreads();
  for (int s = 1; s < 512; s <<= 1) {
    int t = (tid >= s) ? sc[tid - s] : 0;
    __syncthreads();
    sc[tid] += t;
    __syncthreads();
  }
  if (tid < nblk) cnt[b * nblk + tid] = sc[tid] - v;
  if (tid == 511) btot[b] = sc[511];
}

// ---- scanB: 2 blocks; block0 scans A-family totals, block1 B-family ----
__global__ __launch_bounds__(512) void scanB(const int* __restrict__ btot,
                                             int* __restrict__ bbaseA,
                                             int* __restrict__ bbaseB,
                                             int nbE, int nbN) {
  __shared__ int sc[512];
  const int tid = threadIdx.x;
  const int nb = blockIdx.x ? nbN : nbE;
  const int* src = blockIdx.x ? (btot + nbE) : btot;
  int* dst = blockIdx.x ? bbaseB : bbaseA;
  int v = (tid < nb) ? src[tid] : 0;
  sc[tid] = v;
  __syncthreads();
  for (int s = 1; s < 512; s <<= 1) {
    int t = (tid >= s) ? sc[tid - s] : 0;
    __syncthreads();
    sc[tid] += t;
    __syncthreads();
  }
  if (tid < nb) dst[tid] = sc[tid] - v;
  if (tid == 511) dst[nb] = sc[511];
}

// ---- phase 2: decode hei/ew inline + scatter packed 8B entries ----
// PAY entry: p0 = src | (key7 << 20), p1 = ew bits (full fp32)
__global__ __launch_bounds__(256) void binscatter(
    const void* __restrict__ hei, const void* __restrict__ ew, int M,
    const int* __restrict__ cntAB,
    const int* __restrict__ bbaseA, const int* __restrict__ bbaseB,
    i2* __restrict__ PAYA, i2* __restrict__ PAYB,
    int nbE, int nbN, int nblk, const int* __restrict__ flags) {
  __shared__ int baseA[512];
  __shared__ int baseB[512];
  const int tid = threadIdx.x, blk = blockIdx.x;
  for (int b = tid; b < nbE; b += 256) baseA[b] = bbaseA[b] + cntAB[b * nblk + blk];
  for (int b = tid; b < nbN; b += 256) baseB[b] = bbaseB[b] + cntAB[(nbE + b) * nblk + blk];
  __syncthreads();
  const int i64 = flags[1], f16 = flags[0];
  const int mEnd = min(M, (blk + 1) * CH);
  for (int m = blk * CH + tid; m < mEnd; m += 256) {
    int r, c;
    if (i64) {
      r = (int)((const long long*)hei)[m];
      c = (int)((const long long*)hei)[M + m];
    } else {
      r = ((const int*)hei)[m];
      c = ((const int*)hei)[M + m];
    }
    int e = __float_as_int(f16 ? bf2f(((const unsigned short*)ew)[m])
                               : ((const float*)ew)[m]);
    int pA = atomicAdd(&baseA[c >> CW_SHIFT], 1);
    i2 ea; ea[0] = r | ((c & 127) << 20); ea[1] = e;
    PAYA[pA] = ea;
    int pB = atomicAdd(&baseB[r >> CW_SHIFT], 1);
    i2 eb; eb[0] = c | ((r & 127) << 20); eb[1] = e;
    PAYB[pB] = eb;
  }
}

// ---- phase 3 (combined): per-bucket finalize -> CSR entries + offsets + scales ----
__global__ __launch_bounds__(256) void finalize3(
    const i2* __restrict__ PAYA, const int* __restrict__ bbaseA,
    i2* __restrict__ ENTA, int* __restrict__ offE, int E,
    const i2* __restrict__ PAYB, const int* __restrict__ bbaseB,
    i2* __restrict__ ENTB, int* __restrict__ offN, int Nn,
    const float* __restrict__ WMf, float* __restrict__ SCE,
    float* __restrict__ ND, int nbE) {
  __shared__ int cnt[128];
  __shared__ int sc[128];
  __shared__ int cur[128];
  __shared__ float fsum[128];
  int b = blockIdx.x;
  const i2* PAY; const int* bbase; i2* ENT; int* off;
  int nseg, modeB; float* outScale;
  if (b < nbE) {
    PAY = PAYA; bbase = bbaseA; ENT = ENTA; off = offE;
    nseg = E; modeB = 0; outScale = SCE;
  } else {
    b -= nbE;
    PAY = PAYB; bbase = bbaseB; ENT = ENTB; off = offN;
    nseg = Nn; modeB = 1; outScale = ND;
  }
  const int tid = threadIdx.x;
  const int bs = bbase[b], be = bbase[b + 1];
  const int cb = b << CW_SHIFT;
  const int cw = min(128, nseg - cb);
  if (tid < 128) { cnt[tid] = 0; fsum[tid] = 0.f; }
  __syncthreads();
  for (int k = bs + tid; k < be; k += 256)
    atomicAdd(&cnt[(PAY[k][0] >> 20) & 127], 1);
  __syncthreads();
  if (tid < 128) sc[tid] = cnt[tid];
  __syncthreads();
  for (int s = 1; s < 128; s <<= 1) {
    int t = (tid < 128 && tid >= s) ? sc[tid - s] : 0;
    __syncthreads();
    if (tid < 128) sc[tid] += t;
    __syncthreads();
  }
  if (tid < 128) {
    int start = bs + sc[tid] - cnt[tid];
    cur[tid] = start;
    if (tid < cw) off[cb + tid] = start;
  }
  if (tid == 0 && b == ((nseg + 127) >> CW_SHIFT) - 1) off[nseg] = be;
  __syncthreads();
  for (int k = bs + tid; k < be; k += 256) {
    i2 p = PAY[k];
    int key = (p[0] >> 20) & 127;
    int src = p[0] & 0xFFFFF;
    int pos = atomicAdd(&cur[key], 1);
    i2 outp; outp[0] = src; outp[1] = p[1];
    ENT[pos] = outp;
    float add = modeB ? WMf[src] : __int_as_float(p[1]);
    atomicAdd(&fsum[key], add);
  }
  __syncthreads();
  if (tid < cw) {
    float s = fsum[tid] + 1e-8f;
    outScale[cb + tid] = modeB ? rsqrtf(s) : (WMf[cb + tid] / s);
  }
}

// ---- MFMA GEMM v3: LDS-staged weights + fully hoisted A loads ----
template<int KS>
__global__ __launch_bounds__(256) void gemm_mfma3(
    const void* __restrict__ Aptr, const unsigned short* __restrict__ Wt,
    const float* __restrict__ bias, unsigned short* __restrict__ out,
    int Nrows, const int* __restrict__ flags, int relu,
    const float* __restrict__ rowScale) {
  constexpr int K = KS * 32;
  constexpr int KC = K / 8;
  extern __shared__ unsigned short Bs[];
  const int tid = threadIdx.x;
  const int wv = tid >> 6, ln = tid & 63;
  const int lr = ln & 15;
  const int lk = (ln >> 4) << 3;
  const int rowBase = blockIdx.x * 128 + wv * 32;
  const int aF32 = flags ? (flags[0] ? 0 : 1) : 0;

  int ar[2];
#pragma unroll
  for (int t = 0; t < 2; ++t) {
    int r = rowBase + t * 16 + lr;
    ar[t] = (r < Nrows) ? r : (Nrows - 1);
  }

  s8b aR[2][KS];
  if (!aF32) {
#pragma unroll
    for (int t = 0; t < 2; ++t)
#pragma unroll
      for (int ks = 0; ks < KS; ++ks)
        aR[t][ks] = *reinterpret_cast<const s8b*>(
            (const unsigned short*)Aptr + (size_t)ar[t] * K + ks * 32 + lk);
  } else {
#pragma unroll
    for (int t = 0; t < 2; ++t)
#pragma unroll
      for (int ks = 0; ks < KS; ++ks) {
        const float* ap = (const float*)Aptr + (size_t)ar[t] * K + ks * 32 + lk;
        f4 u0 = *reinterpret_cast<const f4*>(ap);
        f4 u1 = *reinterpret_cast<const f4*>(ap + 4);
#pragma unroll
        for (int j = 0; j < 4; ++j) {
          aR[t][ks][j]     = (short)f2bf(u0[j]);
          aR[t][ks][4 + j] = (short)f2bf(u1[j]);
        }
      }
  }

#pragma unroll
  for (int it = 0; it < (128 * KC + 255) / 256; ++it) {
    int ch = it * 256 + tid;
    if (ch < 128 * KC) {
      int row = ch / KC, kc = (ch % KC) << 3;
      us8 v = *reinterpret_cast<const us8*>(Wt + (size_t)row * K + kc);
      int byte = ((row * K + kc) << 1) ^ ((row & 7) << 4);
      *reinterpret_cast<us8*>((char*)Bs + byte) = v;
    }
  }
  __syncthreads();

  f32x4 acc[2][8];
#pragma unroll
  for (int t = 0; t < 2; ++t)
#pragma unroll
    for (int n = 0; n < 8; ++n) acc[t][n] = (f32x4)0.f;

#pragma unroll
  for (int ks = 0; ks < KS; ++ks) {
#pragma unroll
    for (int n = 0; n < 8; ++n) {
      const int brow = n * 16 + lr;
      int byte = ((brow * K + ks * 32 + lk) << 1) ^ ((brow & 7) << 4);
      s8b b = *reinterpret_cast<const s8b*>((const char*)Bs + byte);
      acc[0][n] = __builtin_amdgcn_mfma_f32_16x16x32_bf16(aR[0][ks], b, acc[0][n], 0, 0, 0);
      acc[1][n] = __builtin_amdgcn_mfma_f32_16x16x32_bf16(aR[1][ks], b, acc[1][n], 0, 0, 0);
    }
  }

#pragma unroll
  for (int t = 0; t < 2; ++t) {
    const int orow0 = rowBase + t * 16 + ((ln >> 4) << 2);
#pragma unroll
    for (int n = 0; n < 8; ++n) {
      const int col = n * 16 + lr;
      const float bv = bias[col];
#pragma unroll
      for (int r = 0; r < 4; ++r) {
        int row = orow0 + r;
        if (row >= Nrows) continue;
        float s = acc[t][n][r] + bv;
        if (relu) s = fmaxf(s, 0.f);
        if (rowScale) s *= rowScale[row];
        out[(size_t)row * 128 + col] = f2bf(s);
      }
    }
  }
}

// ---- gather v3: 2 segments/wave, 32 lanes * us4 (8B), 4-deep unroll ----
__global__ __launch_bounds__(256) void gather_edge3(
    const int* __restrict__ off, const i2* __restrict__ ENT,
    const float* __restrict__ sc_e, const unsigned short* __restrict__ X,
    unsigned short* __restrict__ out, int nseg) {
  int seg = blockIdx.x * 8 + (threadIdx.x >> 5);
  if (seg >= nseg) return;
  int d = (threadIdx.x & 31) << 2;
  int k0 = off[seg], k1 = off[seg + 1];
  float a0 = 0.f, a1 = 0.f, a2 = 0.f, a3 = 0.f;
  int k = k0;
  for (; k + 4 <= k1; k += 4) {
    i2 e0 = ENT[k], e1 = ENT[k + 1], e2 = ENT[k + 2], e3 = ENT[k + 3];
    us4 v0 = *reinterpret_cast<const us4*>(X + (size_t)e0[0] * 128 + d);
    us4 v1 = *reinterpret_cast<const us4*>(X + (size_t)e1[0] * 128 + d);
    us4 v2 = *reinterpret_cast<const us4*>(X + (size_t)e2[0] * 128 + d);
    us4 v3 = *reinterpret_cast<const us4*>(X + (size_t)e3[0] * 128 + d);
    float c0 = __int_as_float(e0[1]), c1 = __int_as_float(e1[1]);
    float c2 = __int_as_float(e2[1]), c3 = __int_as_float(e3[1]);
    a0 += c0 * bf2f(v0[0]); a1 += c0 * bf2f(v0[1]); a2 += c0 * bf2f(v0[2]); a3 += c0 * bf2f(v0[3]);
    a0 += c1 * bf2f(v1[0]); a1 += c1 * bf2f(v1[1]); a2 += c1 * bf2f(v1[2]); a3 += c1 * bf2f(v1[3]);
    a0 += c2 * bf2f(v2[0]); a1 += c2 * bf2f(v2[1]); a2 += c2 * bf2f(v2[2]); a3 += c2 * bf2f(v2[3]);
    a0 += c3 * bf2f(v3[0]); a1 += c3 * bf2f(v3[1]); a2 += c3 * bf2f(v3[2]); a3 += c3 * bf2f(v3[3]);
  }
  for (; k < k1; ++k) {
    i2 e = ENT[k];
    us4 v = *reinterpret_cast<const us4*>(X + (size_t)e[0] * 128 + d);
    float c = __int_as_float(e[1]);
    a0 += c * bf2f(v[0]); a1 += c * bf2f(v[1]); a2 += c * bf2f(v[2]); a3 += c * bf2f(v[3]);
  }
  float sc = sc_e[seg];
  us4 o;
  o[0] = f2bf(sc * a0); o[1] = f2bf(sc * a1); o[2] = f2bf(sc * a2); o[3] = f2bf(sc * a3);
  *reinterpret_cast<us4*>(out + (size_t)seg * 128 + d) = o;
}

__global__ __launch_bounds__(256) void gather_node3(
    const int* __restrict__ off, const i2* __restrict__ ENT,
    const float* __restrict__ nd, const unsigned short* __restrict__ HF,
    const unsigned short* __restrict__ H, void* __restrict__ out,
    int nseg, int outF32) {
  int seg = blockIdx.x * 8 + (threadIdx.x >> 5);
  if (seg >= nseg) return;
  int d = (threadIdx.x & 31) << 2;
  int k0 = off[seg], k1 = off[seg + 1];
  float a0 = 0.f, a1 = 0.f, a2 = 0.f, a3 = 0.f;
  int k = k0;
  for (; k + 4 <= k1; k += 4) {
    i2 e0 = ENT[k], e1 = ENT[k + 1], e2 = ENT[k + 2], e3 = ENT[k + 3];
    us4 v0 = *reinterpret_cast<const us4*>(HF + (size_t)e0[0] * 128 + d);
    us4 v1 = *reinterpret_cast<const us4*>(HF + (size_t)e1[0] * 128 + d);
    us4 v2 = *reinterpret_cast<const us4*>(HF + (size_t)e2[0] * 128 + d);
    us4 v3 = *reinterpret_cast<const us4*>(HF + (size_t)e3[0] * 128 + d);
    float c0 = __int_as_float(e0[1]), c1 = __int_as_float(e1[1]);
    float c2 = __int_as_float(e2[1]), c3 = __int_as_float(e3[1]);
    a0 += c0 * bf2f(v0[0]); a1 += c0 * bf2f(v0[1]); a2 += c0 * bf2f(v0[2]); a3 += c0 * bf2f(v0[3]);
    a0 += c1 * bf2f(v1[0]); a1 += c1 * bf2f(v1[1]); a2 += c1 * bf2f(v1[2]); a3 += c1 * bf2f(v1[3]);
    a0 += c2 * bf2f(v2[0]); a1 += c2 * bf2f(v2[1]); a2 += c2 * bf2f(v2[2]); a3 += c2 * bf2f(v2[3]);
    a0 += c3 * bf2f(v3[0]); a1 += c3 * bf2f(v3[1]); a2 += c3 * bf2f(v3[2]); a3 += c3 * bf2f(v3[3]);
  }
  for (; k < k1; ++k) {
    i2 e = ENT[k];
    us4 v = *reinterpret_cast<const us4*>(HF + (size_t)e[0] * 128 + d);
    float c = __int_as_float(e[1]);
    a0 += c * bf2f(v[0]); a1 += c * bf2f(v[1]); a2 += c * bf2f(v[2]); a3 += c * bf2f(v[3]);
  }
  float s = nd[seg];
  us4 h = *reinterpret_cast<const us4*>(H + (size_t)seg * 128 + d);
  float r0 = fmaxf(bf2f(h[0]) + s * a0, 0.f);
  float r1 = fmaxf(bf2f(h[1]) + s * a1, 0.f);
  float r2 = fmaxf(bf2f(h[2]) + s * a2, 0.f);
  float r3 = fmaxf(bf2f(h[3]) + s * a3, 0.f);
  if (outF32) {
    f4 o; o[0] = r0; o[1] = r1; o[2] = r2; o[3] = r3;
    *reinterpret_cast<f4*>((float*)out + (size_t)seg * 128 + d) = o;
  } else {
    us4 o; o[0] = f2bf(r0); o[1] = f2bf(r1); o[2] = f2bf(r2); o[3] = f2bf(r3);
    *reinterpret_cast<us4*>((unsigned short*)out + (size_t)seg * 128 + d) = o;
  }
}

extern "C" void kernel_launch(void* const* d_in, const int* in_sizes, int n_in,
                              void* d_out, int out_size, void* d_ws, size_t ws_size,
                              hipStream_t stream) {
  const void* x   = d_in[0];
  const void* hei = d_in[1];
  const void* wM  = d_in[2];
  const void* ew  = d_in[3];
  const void* fcw = d_in[4];
  const void* fcb = d_in[5];
  const void* cw  = d_in[6];
  const void* cb  = d_in[7];

  const int IN_DIM = 256, D = 128;
  const int N = in_sizes[0] / IN_DIM;
  const int M = in_sizes[1] / 2;
  const int E = in_sizes[2];
  const int L = in_sizes[6] / (D * D);

  const int nbE = (E + 127) >> CW_SHIFT;
  const int nbN = (N + 127) >> CW_SHIFT;
  const int nbT = nbE + nbN;
  const int nblk = (M + CH - 1) / CH;

  float* w = (float*)d_ws;
  size_t o = 0;
  auto alloc = [&](size_t n) { float* p = w + o; o += (n + 3) & ~(size_t)3; return p; };

  // R region: XT+HF later; packed PAY bin arrays earlier (disjoint in time)
  float* R = alloc((size_t)(N + E) * D / 2);
  unsigned short* XT = (unsigned short*)R;
  unsigned short* HF = XT + (size_t)N * D;
  i2*  PAYA = (i2*)R;
  i2*  PAYB = PAYA + M;

  unsigned short* H  = (unsigned short*)alloc((size_t)N * D / 2);
  i2*    ENTA = (i2*)alloc((size_t)M * 2);
  i2*    ENTB = (i2*)alloc((size_t)M * 2);
  int*   cntAB = (int*)alloc((size_t)nbT * nblk);
  int*   btotAB = (int*)alloc(nbT + 2);
  int*   bbaseA = (int*)alloc(nbE + 2);
  int*   bbaseB = (int*)alloc(nbN + 2);
  float* ND   = alloc(N);
  float* SCE  = alloc(E);
  int*   offE = (int*)alloc(E + 1);
  int*   offN = (int*)alloc(N + 1);
  float* WMf  = alloc(E);
  unsigned short* FCWT = (unsigned short*)alloc((size_t)IN_DIM * D / 2);
  float* FCB  = alloc(D);
  unsigned short* CWT = (unsigned short*)alloc((size_t)L * D * D / 2);
  float* CBf  = alloc((size_t)L * D);
  int*   FLAGS = (int*)alloc(16);

  detect_kernel<<<1, 64, 0, stream>>>((const unsigned int*)x, (const unsigned int*)hei, FLAGS);

  bin_count<<<nblk, 256, 0, stream>>>(hei, M, cntAB, nbE, nbN, nblk, FLAGS);
  {
    int ntot = E + IN_DIM * D + D + L * D * D + L * D;
    cvt_params<<<(ntot + 255) / 256, 256, 0, stream>>>(wM, fcw, fcb, cw, cb,
                                                       WMf, FCWT, FCB, CWT, CBf,
                                                       E, L, FLAGS);
  }

  scanA<<<nbT, 512, 0, stream>>>(cntAB, btotAB, nblk);
  scanB<<<2, 512, 0, stream>>>(btotAB, bbaseA, bbaseB, nbE, nbN);

  binscatter<<<nblk, 256, 0, stream>>>(hei, ew, M, cntAB, bbaseA, bbaseB,
                                       PAYA, PAYB, nbE, nbN, nblk, FLAGS);

  finalize3<<<nbT, 256, 0, stream>>>(PAYA, bbaseA, ENTA, offE, E,
                                     PAYB, bbaseB, ENTB, offN, N,
                                     WMf, SCE, ND, nbE);

  // h0 = relu(x @ fc_w + fc_b)
  gemm_mfma3<8><<<(N + 127) / 128, 256, 128 * 256 * 2, stream>>>(
      x, FCWT, FCB, H, N, FLAGS, 1, nullptr);

  int segBlkE = (E + 7) / 8, segBlkN = (N + 7) / 8;
  for (int l = 0; l < L; ++l) {
    // xt' = nd[r] * (h @ conv_w[l] + conv_b[l])
    gemm_mfma3<4><<<(N + 127) / 128, 256, 128 * 128 * 2, stream>>>(
        H, CWT + (size_t)l * D * D, CBf + (size_t)l * D, XT, N,
        (const int*)nullptr, 0, ND);
    gather_edge3<<<segBlkE, 256, 0, stream>>>(offE, ENTA, SCE, XT, HF, E);
    gather_node3<<<segBlkN, 256, 0, stream>>>(
        offN, ENTB, ND, HF, H,
        (l == L - 1) ? d_out : (void*)H, N, (l == L - 1) ? 1 : 0);
  }
}

// Round 13
// 307.527 us; speedup vs baseline: 1.1331x; 1.0466x over previous
//
#include <hip/hip_runtime.h>
#include <hip/hip_bf16.h>
#include <stdint.h>

typedef __attribute__((ext_vector_type(4))) float f4;
typedef __attribute__((ext_vector_type(2))) float f2;
typedef __attribute__((ext_vector_type(2))) int i2;
typedef __attribute__((ext_vector_type(8))) unsigned short us8;
typedef __attribute__((ext_vector_type(4))) unsigned short us4;
typedef __attribute__((ext_vector_type(2))) unsigned short us2;
typedef __attribute__((ext_vector_type(8))) short s8b;    // MFMA A/B frag (8 bf16)
typedef __attribute__((ext_vector_type(4))) float f32x4;  // MFMA C/D frag

#define CW_SHIFT 8            // 256 cols per bucket (bigger chunks -> less store RMW)
#define CW (1 << CW_SHIFT)
#define CH 2048               // edges per block in bin phases (313 blocks)

__device__ __forceinline__ float bf2f(unsigned short u) {
  union { unsigned int i; float f; } t; t.i = ((unsigned int)u) << 16; return t.f;
}
__device__ __forceinline__ unsigned short f2bf(float f) {
  union { float f; unsigned int i; } t; t.f = f;
  unsigned int u = t.i;
  return (unsigned short)((u + 0x7FFFu + ((u >> 16) & 1u)) >> 16);
}
__device__ __forceinline__ float cvtload(const void* p, int i, int f16) {
  return f16 ? bf2f(((const unsigned short*)p)[i]) : ((const float*)p)[i];
}

// ---- dtype detection ----
__global__ void detect_kernel(const unsigned int* __restrict__ xb,
                              const unsigned int* __restrict__ ib,
                              int* __restrict__ flags) {
  if (threadIdx.x == 0) {
    int cnt = 0;
    for (int i = 0; i < 256; ++i) {
      unsigned int e = (xb[i] >> 7) & 0xffu;
      if (e >= 110u && e <= 135u) ++cnt;
    }
    flags[0] = (cnt >= 180) ? 1 : 0;
    int zc = 0;
    for (int i = 0; i < 128; ++i) if (ib[2 * i + 1] == 0u) ++zc;
    flags[1] = (zc >= 120) ? 1 : 0;
  }
}

// ---- fused parameter convert: wM, fc_w^T, fc_b, conv_w^T, conv_b ----
__global__ void cvt_params(const void* __restrict__ wM, const void* __restrict__ fcw,
                           const void* __restrict__ fcb, const void* __restrict__ cw,
                           const void* __restrict__ cb,
                           float* __restrict__ WMf, unsigned short* __restrict__ FCWT,
                           float* __restrict__ FCB, unsigned short* __restrict__ CWT,
                           float* __restrict__ CBf,
                           int E, int L, const int* __restrict__ flags) {
  const int IN_DIM = 256, D = 128;
  int i = blockIdx.x * 256 + threadIdx.x;
  const int f16 = flags[0];
  if (i < E) { WMf[i] = cvtload(wM, i, f16); return; }
  i -= E;
  if (i < IN_DIM * D) {
    int c = i >> 8, k = i & 255;
    FCWT[i] = f2bf(cvtload(fcw, k * D + c, f16));
    return;
  }
  i -= IN_DIM * D;
  if (i < D) { FCB[i] = cvtload(fcb, i, f16); return; }
  i -= D;
  if (i < L * D * D) {
    int l = i >> 14, rem = i & 16383;
    int c = rem >> 7, k = rem & 127;
    CWT[i] = f2bf(cvtload(cw, l * D * D + k * D + c, f16));
    return;
  }
  i -= L * D * D;
  if (i < L * D) CBf[i] = cvtload(cb, i, f16);
}

// ---- phase 1: per-(block,bucket) histograms only ----
__global__ __launch_bounds__(256) void bin_count(
    const void* __restrict__ hei, int M, int* __restrict__ cntAB,
    int nbE, int nbN, int nblk, const int* __restrict__ flags) {
  __shared__ int hA[256];
  __shared__ int hB[256];
  const int tid = threadIdx.x, blk = blockIdx.x;
  hA[tid] = 0; hB[tid] = 0;
  __syncthreads();
  const int i64 = flags[1];
  const int mEnd = min(M, (blk + 1) * CH);
  for (int m = blk * CH + tid; m < mEnd; m += 256) {
    int r, c;
    if (i64) {
      r = (int)((const long long*)hei)[m];
      c = (int)((const long long*)hei)[M + m];
    } else {
      r = ((const int*)hei)[m];
      c = ((const int*)hei)[M + m];
    }
    atomicAdd(&hA[c >> CW_SHIFT], 1);
    atomicAdd(&hB[r >> CW_SHIFT], 1);
  }
  __syncthreads();
  if (tid < nbE) cntAB[tid * nblk + blk] = hA[tid];
  if (tid < nbN) cntAB[(nbE + tid) * nblk + blk] = hB[tid];
}

// ---- scanA: per-bucket exclusive scan over nblk block counts (both families) ----
__global__ __launch_bounds__(512) void scanA(int* __restrict__ cnt,
                                             int* __restrict__ btot, int nblk) {
  __shared__ int sc[512];
  const int tid = threadIdx.x, b = blockIdx.x;
  int v = (tid < nblk) ? cnt[b * nblk + tid] : 0;
  sc[tid] = v;
  __syncthreads();
  for (int s = 1; s < 512; s <<= 1) {
    int t = (tid >= s) ? sc[tid - s] : 0;
    __syncthreads();
    sc[tid] += t;
    __syncthreads();
  }
  if (tid < nblk) cnt[b * nblk + tid] = sc[tid] - v;
  if (tid == 511) btot[b] = sc[511];
}

// ---- scanB: 2 blocks; block0 scans A-family totals, block1 B-family ----
__global__ __launch_bounds__(512) void scanB(const int* __restrict__ btot,
                                             int* __restrict__ bbaseA,
                                             int* __restrict__ bbaseB,
                                             int nbE, int nbN) {
  __shared__ int sc[512];
  const int tid = threadIdx.x;
  const int nb = blockIdx.x ? nbN : nbE;
  const int* src = blockIdx.x ? (btot + nbE) : btot;
  int* dst = blockIdx.x ? bbaseB : bbaseA;
  int v = (tid < nb) ? src[tid] : 0;
  sc[tid] = v;
  __syncthreads();
  for (int s = 1; s < 512; s <<= 1) {
    int t = (tid >= s) ? sc[tid - s] : 0;
    __syncthreads();
    sc[tid] += t;
    __syncthreads();
  }
  if (tid < nb) dst[tid] = sc[tid] - v;
  if (tid == 511) dst[nb] = sc[511];
}

// ---- phase 2: decode hei/ew inline + scatter packed 8B entries ----
// PAY entry: p0 = src | (key8 << 20), p1 = ew bits (full fp32)
__global__ __launch_bounds__(256) void binscatter(
    const void* __restrict__ hei, const void* __restrict__ ew, int M,
    const int* __restrict__ cntAB,
    const int* __restrict__ bbaseA, const int* __restrict__ bbaseB,
    i2* __restrict__ PAYA, i2* __restrict__ PAYB,
    int nbE, int nbN, int nblk, const int* __restrict__ flags) {
  __shared__ int baseA[256];
  __shared__ int baseB[256];
  const int tid = threadIdx.x, blk = blockIdx.x;
  if (tid < nbE) baseA[tid] = bbaseA[tid] + cntAB[tid * nblk + blk];
  if (tid < nbN) baseB[tid] = bbaseB[tid] + cntAB[(nbE + tid) * nblk + blk];
  __syncthreads();
  const int i64 = flags[1], f16 = flags[0];
  const int mEnd = min(M, (blk + 1) * CH);
  for (int m = blk * CH + tid; m < mEnd; m += 256) {
    int r, c;
    if (i64) {
      r = (int)((const long long*)hei)[m];
      c = (int)((const long long*)hei)[M + m];
    } else {
      r = ((const int*)hei)[m];
      c = ((const int*)hei)[M + m];
    }
    int e = __float_as_int(f16 ? bf2f(((const unsigned short*)ew)[m])
                               : ((const float*)ew)[m]);
    int pA = atomicAdd(&baseA[c >> CW_SHIFT], 1);
    i2 ea; ea[0] = r | ((c & (CW - 1)) << 20); ea[1] = e;
    PAYA[pA] = ea;
    int pB = atomicAdd(&baseB[r >> CW_SHIFT], 1);
    i2 eb; eb[0] = c | ((r & (CW - 1)) << 20); eb[1] = e;
    PAYB[pB] = eb;
  }
}

// ---- phase 3 (combined): per-bucket finalize -> CSR entries + offsets + scales ----
__global__ __launch_bounds__(256) void finalize3(
    const i2* __restrict__ PAYA, const int* __restrict__ bbaseA,
    i2* __restrict__ ENTA, int* __restrict__ offE, int E,
    const i2* __restrict__ PAYB, const int* __restrict__ bbaseB,
    i2* __restrict__ ENTB, int* __restrict__ offN, int Nn,
    const float* __restrict__ WMf, float* __restrict__ SCE,
    float* __restrict__ ND, int nbE) {
  __shared__ int cnt[CW];
  __shared__ int sc[CW];
  __shared__ int cur[CW];
  __shared__ float fsum[CW];
  int b = blockIdx.x;
  const i2* PAY; const int* bbase; i2* ENT; int* off;
  int nseg, modeB; float* outScale;
  if (b < nbE) {
    PAY = PAYA; bbase = bbaseA; ENT = ENTA; off = offE;
    nseg = E; modeB = 0; outScale = SCE;
  } else {
    b -= nbE;
    PAY = PAYB; bbase = bbaseB; ENT = ENTB; off = offN;
    nseg = Nn; modeB = 1; outScale = ND;
  }
  const int tid = threadIdx.x;
  const int bs = bbase[b], be = bbase[b + 1];
  const int cb = b << CW_SHIFT;
  const int cw = min(CW, nseg - cb);
  for (int i = tid; i < CW; i += 256) { cnt[i] = 0; fsum[i] = 0.f; }
  __syncthreads();
  for (int k = bs + tid; k < be; k += 256)
    atomicAdd(&cnt[(PAY[k][0] >> 20) & (CW - 1)], 1);
  __syncthreads();
  for (int i = tid; i < CW; i += 256) sc[i] = cnt[i];
  __syncthreads();
  // exclusive scan over CW=256 elements with 256 threads
  for (int s = 1; s < CW; s <<= 1) {
    int t = (tid >= s) ? sc[tid - s] : 0;
    __syncthreads();
    sc[tid] += t;
    __syncthreads();
  }
  {
    int start = bs + sc[tid] - cnt[tid];
    cur[tid] = start;
    if (tid < cw) off[cb + tid] = start;
  }
  if (tid == 0 && b == ((nseg + CW - 1) >> CW_SHIFT) - 1) off[nseg] = be;
  __syncthreads();
  for (int k = bs + tid; k < be; k += 256) {
    i2 p = PAY[k];
    int key = (p[0] >> 20) & (CW - 1);
    int src = p[0] & 0xFFFFF;
    int pos = atomicAdd(&cur[key], 1);
    i2 outp; outp[0] = src; outp[1] = p[1];
    ENT[pos] = outp;
    float add = modeB ? WMf[src] : __int_as_float(p[1]);
    atomicAdd(&fsum[key], add);
  }
  __syncthreads();
  if (tid < cw) {
    float s = fsum[tid] + 1e-8f;
    outScale[cb + tid] = modeB ? rsqrtf(s) : (WMf[cb + tid] / s);
  }
}

// ---- MFMA GEMM v3: LDS-staged weights + fully hoisted A loads ----
template<int KS>
__global__ __launch_bounds__(256) void gemm_mfma3(
    const void* __restrict__ Aptr, const unsigned short* __restrict__ Wt,
    const float* __restrict__ bias, unsigned short* __restrict__ out,
    int Nrows, const int* __restrict__ flags, int relu,
    const float* __restrict__ rowScale) {
  constexpr int K = KS * 32;
  constexpr int KC = K / 8;
  extern __shared__ unsigned short Bs[];
  const int tid = threadIdx.x;
  const int wv = tid >> 6, ln = tid & 63;
  const int lr = ln & 15;
  const int lk = (ln >> 4) << 3;
  const int rowBase = blockIdx.x * 128 + wv * 32;
  const int aF32 = flags ? (flags[0] ? 0 : 1) : 0;

  int ar[2];
#pragma unroll
  for (int t = 0; t < 2; ++t) {
    int r = rowBase + t * 16 + lr;
    ar[t] = (r < Nrows) ? r : (Nrows - 1);
  }

  s8b aR[2][KS];
  if (!aF32) {
#pragma unroll
    for (int t = 0; t < 2; ++t)
#pragma unroll
      for (int ks = 0; ks < KS; ++ks)
        aR[t][ks] = *reinterpret_cast<const s8b*>(
            (const unsigned short*)Aptr + (size_t)ar[t] * K + ks * 32 + lk);
  } else {
#pragma unroll
    for (int t = 0; t < 2; ++t)
#pragma unroll
      for (int ks = 0; ks < KS; ++ks) {
        const float* ap = (const float*)Aptr + (size_t)ar[t] * K + ks * 32 + lk;
        f4 u0 = *reinterpret_cast<const f4*>(ap);
        f4 u1 = *reinterpret_cast<const f4*>(ap + 4);
#pragma unroll
        for (int j = 0; j < 4; ++j) {
          aR[t][ks][j]     = (short)f2bf(u0[j]);
          aR[t][ks][4 + j] = (short)f2bf(u1[j]);
        }
      }
  }

#pragma unroll
  for (int it = 0; it < (128 * KC + 255) / 256; ++it) {
    int ch = it * 256 + tid;
    if (ch < 128 * KC) {
      int row = ch / KC, kc = (ch % KC) << 3;
      us8 v = *reinterpret_cast<const us8*>(Wt + (size_t)row * K + kc);
      int byte = ((row * K + kc) << 1) ^ ((row & 7) << 4);
      *reinterpret_cast<us8*>((char*)Bs + byte) = v;
    }
  }
  __syncthreads();

  f32x4 acc[2][8];
#pragma unroll
  for (int t = 0; t < 2; ++t)
#pragma unroll
    for (int n = 0; n < 8; ++n) acc[t][n] = (f32x4)0.f;

#pragma unroll
  for (int ks = 0; ks < KS; ++ks) {
#pragma unroll
    for (int n = 0; n < 8; ++n) {
      const int brow = n * 16 + lr;
      int byte = ((brow * K + ks * 32 + lk) << 1) ^ ((brow & 7) << 4);
      s8b b = *reinterpret_cast<const s8b*>((const char*)Bs + byte);
      acc[0][n] = __builtin_amdgcn_mfma_f32_16x16x32_bf16(aR[0][ks], b, acc[0][n], 0, 0, 0);
      acc[1][n] = __builtin_amdgcn_mfma_f32_16x16x32_bf16(aR[1][ks], b, acc[1][n], 0, 0, 0);
    }
  }

#pragma unroll
  for (int t = 0; t < 2; ++t) {
    const int orow0 = rowBase + t * 16 + ((ln >> 4) << 2);
#pragma unroll
    for (int n = 0; n < 8; ++n) {
      const int col = n * 16 + lr;
      const float bv = bias[col];
#pragma unroll
      for (int r = 0; r < 4; ++r) {
        int row = orow0 + r;
        if (row >= Nrows) continue;
        float s = acc[t][n][r] + bv;
        if (relu) s = fmaxf(s, 0.f);
        if (rowScale) s *= rowScale[row];
        out[(size_t)row * 128 + col] = f2bf(s);
      }
    }
  }
}

// ---- gather v5: 4 segments/wave, 16 lanes * us8 (16B) per row, 4-deep unroll ----
__global__ __launch_bounds__(256) void gather_edge3(
    const int* __restrict__ off, const i2* __restrict__ ENT,
    const float* __restrict__ sc_e, const unsigned short* __restrict__ X,
    unsigned short* __restrict__ out, int nseg) {
  int seg = blockIdx.x * 16 + (threadIdx.x >> 4);
  if (seg >= nseg) return;
  int d = (threadIdx.x & 15) << 3;
  int k0 = off[seg], k1 = off[seg + 1];
  float a0 = 0.f, a1 = 0.f, a2 = 0.f, a3 = 0.f, a4 = 0.f, a5 = 0.f, a6 = 0.f, a7 = 0.f;
  int k = k0;
  for (; k + 4 <= k1; k += 4) {
    i2 e0 = ENT[k], e1 = ENT[k + 1], e2 = ENT[k + 2], e3 = ENT[k + 3];
    us8 v0 = *reinterpret_cast<const us8*>(X + (size_t)e0[0] * 128 + d);
    us8 v1 = *reinterpret_cast<const us8*>(X + (size_t)e1[0] * 128 + d);
    us8 v2 = *reinterpret_cast<const us8*>(X + (size_t)e2[0] * 128 + d);
    us8 v3 = *reinterpret_cast<const us8*>(X + (size_t)e3[0] * 128 + d);
    float c0 = __int_as_float(e0[1]), c1 = __int_as_float(e1[1]);
    float c2 = __int_as_float(e2[1]), c3 = __int_as_float(e3[1]);
    a0 += c0 * bf2f(v0[0]); a1 += c0 * bf2f(v0[1]); a2 += c0 * bf2f(v0[2]); a3 += c0 * bf2f(v0[3]);
    a4 += c0 * bf2f(v0[4]); a5 += c0 * bf2f(v0[5]); a6 += c0 * bf2f(v0[6]); a7 += c0 * bf2f(v0[7]);
    a0 += c1 * bf2f(v1[0]); a1 += c1 * bf2f(v1[1]); a2 += c1 * bf2f(v1[2]); a3 += c1 * bf2f(v1[3]);
    a4 += c1 * bf2f(v1[4]); a5 += c1 * bf2f(v1[5]); a6 += c1 * bf2f(v1[6]); a7 += c1 * bf2f(v1[7]);
    a0 += c2 * bf2f(v2[0]); a1 += c2 * bf2f(v2[1]); a2 += c2 * bf2f(v2[2]); a3 += c2 * bf2f(v2[3]);
    a4 += c2 * bf2f(v2[4]); a5 += c2 * bf2f(v2[5]); a6 += c2 * bf2f(v2[6]); a7 += c2 * bf2f(v2[7]);
    a0 += c3 * bf2f(v3[0]); a1 += c3 * bf2f(v3[1]); a2 += c3 * bf2f(v3[2]); a3 += c3 * bf2f(v3[3]);
    a4 += c3 * bf2f(v3[4]); a5 += c3 * bf2f(v3[5]); a6 += c3 * bf2f(v3[6]); a7 += c3 * bf2f(v3[7]);
  }
  for (; k < k1; ++k) {
    i2 e = ENT[k];
    us8 v = *reinterpret_cast<const us8*>(X + (size_t)e[0] * 128 + d);
    float c = __int_as_float(e[1]);
    a0 += c * bf2f(v[0]); a1 += c * bf2f(v[1]); a2 += c * bf2f(v[2]); a3 += c * bf2f(v[3]);
    a4 += c * bf2f(v[4]); a5 += c * bf2f(v[5]); a6 += c * bf2f(v[6]); a7 += c * bf2f(v[7]);
  }
  float sc = sc_e[seg];
  us8 o;
  o[0] = f2bf(sc * a0); o[1] = f2bf(sc * a1); o[2] = f2bf(sc * a2); o[3] = f2bf(sc * a3);
  o[4] = f2bf(sc * a4); o[5] = f2bf(sc * a5); o[6] = f2bf(sc * a6); o[7] = f2bf(sc * a7);
  *reinterpret_cast<us8*>(out + (size_t)seg * 128 + d) = o;
}

__global__ __launch_bounds__(256) void gather_node3(
    const int* __restrict__ off, const i2* __restrict__ ENT,
    const float* __restrict__ nd, const unsigned short* __restrict__ HF,
    const unsigned short* __restrict__ H, void* __restrict__ out,
    int nseg, int outF32) {
  int seg = blockIdx.x * 16 + (threadIdx.x >> 4);
  if (seg >= nseg) return;
  int d = (threadIdx.x & 15) << 3;
  int k0 = off[seg], k1 = off[seg + 1];
  float a0 = 0.f, a1 = 0.f, a2 = 0.f, a3 = 0.f, a4 = 0.f, a5 = 0.f, a6 = 0.f, a7 = 0.f;
  int k = k0;
  for (; k + 4 <= k1; k += 4) {
    i2 e0 = ENT[k], e1 = ENT[k + 1], e2 = ENT[k + 2], e3 = ENT[k + 3];
    us8 v0 = *reinterpret_cast<const us8*>(HF + (size_t)e0[0] * 128 + d);
    us8 v1 = *reinterpret_cast<const us8*>(HF + (size_t)e1[0] * 128 + d);
    us8 v2 = *reinterpret_cast<const us8*>(HF + (size_t)e2[0] * 128 + d);
    us8 v3 = *reinterpret_cast<const us8*>(HF + (size_t)e3[0] * 128 + d);
    float c0 = __int_as_float(e0[1]), c1 = __int_as_float(e1[1]);
    float c2 = __int_as_float(e2[1]), c3 = __int_as_float(e3[1]);
    a0 += c0 * bf2f(v0[0]); a1 += c0 * bf2f(v0[1]); a2 += c0 * bf2f(v0[2]); a3 += c0 * bf2f(v0[3]);
    a4 += c0 * bf2f(v0[4]); a5 += c0 * bf2f(v0[5]); a6 += c0 * bf2f(v0[6]); a7 += c0 * bf2f(v0[7]);
    a0 += c1 * bf2f(v1[0]); a1 += c1 * bf2f(v1[1]); a2 += c1 * bf2f(v1[2]); a3 += c1 * bf2f(v1[3]);
    a4 += c1 * bf2f(v1[4]); a5 += c1 * bf2f(v1[5]); a6 += c1 * bf2f(v1[6]); a7 += c1 * bf2f(v1[7]);
    a0 += c2 * bf2f(v2[0]); a1 += c2 * bf2f(v2[1]); a2 += c2 * bf2f(v2[2]); a3 += c2 * bf2f(v2[3]);
    a4 += c2 * bf2f(v2[4]); a5 += c2 * bf2f(v2[5]); a6 += c2 * bf2f(v2[6]); a7 += c2 * bf2f(v2[7]);
    a0 += c3 * bf2f(v3[0]); a1 += c3 * bf2f(v3[1]); a2 += c3 * bf2f(v3[2]); a3 += c3 * bf2f(v3[3]);
    a4 += c3 * bf2f(v3[4]); a5 += c3 * bf2f(v3[5]); a6 += c3 * bf2f(v3[6]); a7 += c3 * bf2f(v3[7]);
  }
  for (; k < k1; ++k) {
    i2 e = ENT[k];
    us8 v = *reinterpret_cast<const us8*>(HF + (size_t)e[0] * 128 + d);
    float c = __int_as_float(e[1]);
    a0 += c * bf2f(v[0]); a1 += c * bf2f(v[1]); a2 += c * bf2f(v[2]); a3 += c * bf2f(v[3]);
    a4 += c * bf2f(v[4]); a5 += c * bf2f(v[5]); a6 += c * bf2f(v[6]); a7 += c * bf2f(v[7]);
  }
  float s = nd[seg];
  us8 h = *reinterpret_cast<const us8*>(H + (size_t)seg * 128 + d);
  float r0 = fmaxf(bf2f(h[0]) + s * a0, 0.f);
  float r1 = fmaxf(bf2f(h[1]) + s * a1, 0.f);
  float r2 = fmaxf(bf2f(h[2]) + s * a2, 0.f);
  float r3 = fmaxf(bf2f(h[3]) + s * a3, 0.f);
  float r4 = fmaxf(bf2f(h[4]) + s * a4, 0.f);
  float r5 = fmaxf(bf2f(h[5]) + s * a5, 0.f);
  float r6 = fmaxf(bf2f(h[6]) + s * a6, 0.f);
  float r7 = fmaxf(bf2f(h[7]) + s * a7, 0.f);
  if (outF32) {
    float* op = (float*)out + (size_t)seg * 128 + d;
    f4 o0, o1;
    o0[0] = r0; o0[1] = r1; o0[2] = r2; o0[3] = r3;
    o1[0] = r4; o1[1] = r5; o1[2] = r6; o1[3] = r7;
    *reinterpret_cast<f4*>(op) = o0;
    *reinterpret_cast<f4*>(op + 4) = o1;
  } else {
    us8 o;
    o[0] = f2bf(r0); o[1] = f2bf(r1); o[2] = f2bf(r2); o[3] = f2bf(r3);
    o[4] = f2bf(r4); o[5] = f2bf(r5); o[6] = f2bf(r6); o[7] = f2bf(r7);
    *reinterpret_cast<us8*>((unsigned short*)out + (size_t)seg * 128 + d) = o;
  }
}

extern "C" void kernel_launch(void* const* d_in, const int* in_sizes, int n_in,
                              void* d_out, int out_size, void* d_ws, size_t ws_size,
                              hipStream_t stream) {
  const void* x   = d_in[0];
  const void* hei = d_in[1];
  const void* wM  = d_in[2];
  const void* ew  = d_in[3];
  const void* fcw = d_in[4];
  const void* fcb = d_in[5];
  const void* cw  = d_in[6];
  const void* cb  = d_in[7];

  const int IN_DIM = 256, D = 128;
  const int N = in_sizes[0] / IN_DIM;
  const int M = in_sizes[1] / 2;
  const int E = in_sizes[2];
  const int L = in_sizes[6] / (D * D);

  const int nbE = (E + CW - 1) >> CW_SHIFT;
  const int nbN = (N + CW - 1) >> CW_SHIFT;
  const int nbT = nbE + nbN;
  const int nblk = (M + CH - 1) / CH;

  float* w = (float*)d_ws;
  size_t o = 0;
  auto alloc = [&](size_t n) { float* p = w + o; o += (n + 3) & ~(size_t)3; return p; };

  // R region: XT+HF later; packed PAY bin arrays earlier (disjoint in time)
  float* R = alloc((size_t)(N + E) * D / 2);
  unsigned short* XT = (unsigned short*)R;
  unsigned short* HF = XT + (size_t)N * D;
  i2*  PAYA = (i2*)R;
  i2*  PAYB = PAYA + M;

  unsigned short* H  = (unsigned short*)alloc((size_t)N * D / 2);
  i2*    ENTA = (i2*)alloc((size_t)M * 2);
  i2*    ENTB = (i2*)alloc((size_t)M * 2);
  int*   cntAB = (int*)alloc((size_t)nbT * nblk);
  int*   btotAB = (int*)alloc(nbT + 2);
  int*   bbaseA = (int*)alloc(nbE + 2);
  int*   bbaseB = (int*)alloc(nbN + 2);
  float* ND   = alloc(N);
  float* SCE  = alloc(E);
  int*   offE = (int*)alloc(E + 1);
  int*   offN = (int*)alloc(N + 1);
  float* WMf  = alloc(E);
  unsigned short* FCWT = (unsigned short*)alloc((size_t)IN_DIM * D / 2);
  float* FCB  = alloc(D);
  unsigned short* CWT = (unsigned short*)alloc((size_t)L * D * D / 2);
  float* CBf  = alloc((size_t)L * D);
  int*   FLAGS = (int*)alloc(16);

  detect_kernel<<<1, 64, 0, stream>>>((const unsigned int*)x, (const unsigned int*)hei, FLAGS);

  bin_count<<<nblk, 256, 0, stream>>>(hei, M, cntAB, nbE, nbN, nblk, FLAGS);
  {
    int ntot = E + IN_DIM * D + D + L * D * D + L * D;
    cvt_params<<<(ntot + 255) / 256, 256, 0, stream>>>(wM, fcw, fcb, cw, cb,
                                                       WMf, FCWT, FCB, CWT, CBf,
                                                       E, L, FLAGS);
  }

  scanA<<<nbT, 512, 0, stream>>>(cntAB, btotAB, nblk);
  scanB<<<2, 512, 0, stream>>>(btotAB, bbaseA, bbaseB, nbE, nbN);

  binscatter<<<nblk, 256, 0, stream>>>(hei, ew, M, cntAB, bbaseA, bbaseB,
                                       PAYA, PAYB, nbE, nbN, nblk, FLAGS);

  finalize3<<<nbT, 256, 0, stream>>>(PAYA, bbaseA, ENTA, offE, E,
                                     PAYB, bbaseB, ENTB, offN, N,
                                     WMf, SCE, ND, nbE);

  // h0 = relu(x @ fc_w + fc_b)
  gemm_mfma3<8><<<(N + 127) / 128, 256, 128 * 256 * 2, stream>>>(
      x, FCWT, FCB, H, N, FLAGS, 1, nullptr);

  int segBlkE = (E + 15) / 16, segBlkN = (N + 15) / 16;
  for (int l = 0; l < L; ++l) {
    // xt' = nd[r] * (h @ conv_w[l] + conv_b[l])
    gemm_mfma3<4><<<(N + 127) / 128, 256, 128 * 128 * 2, stream>>>(
        H, CWT + (size_t)l * D * D, CBf + (size_t)l * D, XT, N,
        (const int*)nullptr, 0, ND);
    gather_edge3<<<segBlkE, 256, 0, stream>>>(offE, ENTA, SCE, XT, HF, E);
    gather_node3<<<segBlkN, 256, 0, stream>>>(
        offN, ENTB, ND, HF, H,
        (l == L - 1) ? d_out : (void*)H, N, (l == L - 1) ? 1 : 0);
  }
}

// Round 14
// 306.141 us; speedup vs baseline: 1.1382x; 1.0045x over previous
//
#include <hip/hip_runtime.h>
#include <hip/hip_bf16.h>
#include <stdint.h>

typedef __attribute__((ext_vector_type(4))) float f4;
typedef __attribute__((ext_vector_type(2))) float f2;
typedef __attribute__((ext_vector_type(2))) int i2;
typedef __attribute__((ext_vector_type(8))) unsigned short us8;
typedef __attribute__((ext_vector_type(4))) unsigned short us4;
typedef __attribute__((ext_vector_type(8))) short s8b;    // MFMA A/B frag (8 bf16)
typedef __attribute__((ext_vector_type(4))) float f32x4;  // MFMA C/D frag

#define CW_SHIFT 8            // 256 cols per bucket
#define CW (1 << CW_SHIFT)
#define CH 2048               // edges per block in scatter phase (313 blocks)
#define CAP_SHIFT 13          // 8192 slots per bucket (max real bucket ~3600)
#define CAP (1 << CAP_SHIFT)

__device__ __forceinline__ float bf2f(unsigned short u) {
  union { unsigned int i; float f; } t; t.i = ((unsigned int)u) << 16; return t.f;
}
__device__ __forceinline__ unsigned short f2bf(float f) {
  union { float f; unsigned int i; } t; t.f = f;
  unsigned int u = t.i;
  return (unsigned short)((u + 0x7FFFu + ((u >> 16) & 1u)) >> 16);
}
__device__ __forceinline__ float cvtload(const void* p, int i, int f16) {
  return f16 ? bf2f(((const unsigned short*)p)[i]) : ((const float*)p)[i];
}

// ---- dtype detection + cursor zeroing ----
__global__ void detect_kernel(const unsigned int* __restrict__ xb,
                              const unsigned int* __restrict__ ib,
                              int* __restrict__ flags,
                              int* __restrict__ gcur, int ncur) {
  for (int i = threadIdx.x; i < ncur; i += 64) gcur[i] = 0;
  if (threadIdx.x == 0) {
    int cnt = 0;
    for (int i = 0; i < 256; ++i) {
      unsigned int e = (xb[i] >> 7) & 0xffu;
      if (e >= 110u && e <= 135u) ++cnt;
    }
    flags[0] = (cnt >= 180) ? 1 : 0;
    int zc = 0;
    for (int i = 0; i < 128; ++i) if (ib[2 * i + 1] == 0u) ++zc;
    flags[1] = (zc >= 120) ? 1 : 0;
  }
}

// ---- fused parameter convert: wM, fc_w^T, fc_b, conv_w^T, conv_b ----
__global__ void cvt_params(const void* __restrict__ wM, const void* __restrict__ fcw,
                           const void* __restrict__ fcb, const void* __restrict__ cw,
                           const void* __restrict__ cb,
                           float* __restrict__ WMf, unsigned short* __restrict__ FCWT,
                           float* __restrict__ FCB, unsigned short* __restrict__ CWT,
                           float* __restrict__ CBf,
                           int E, int L, const int* __restrict__ flags) {
  const int IN_DIM = 256, D = 128;
  int i = blockIdx.x * 256 + threadIdx.x;
  const int f16 = flags[0];
  if (i < E) { WMf[i] = cvtload(wM, i, f16); return; }
  i -= E;
  if (i < IN_DIM * D) {
    int c = i >> 8, k = i & 255;
    FCWT[i] = f2bf(cvtload(fcw, k * D + c, f16));
    return;
  }
  i -= IN_DIM * D;
  if (i < D) { FCB[i] = cvtload(fcb, i, f16); return; }
  i -= D;
  if (i < L * D * D) {
    int l = i >> 14, rem = i & 16383;
    int c = rem >> 7, k = rem & 127;
    CWT[i] = f2bf(cvtload(cw, l * D * D + k * D + c, f16));
    return;
  }
  i -= L * D * D;
  if (i < L * D) CBf[i] = cvtload(cb, i, f16);
}

// ---- single-pass fused scatter: decode -> LDS stage -> chunk-reserve -> slot write ----
// SLOT entry: p0 = src | (key8 << 20), p1 = ew bits. Slot base = bucket << CAP_SHIFT.
__global__ __launch_bounds__(256) void fused_scatter(
    const void* __restrict__ hei, const void* __restrict__ ew, int M,
    int* __restrict__ gcurA, int* __restrict__ gcurB,
    i2* __restrict__ SLOTA, i2* __restrict__ SLOTB,
    int nbE, int nbN, const int* __restrict__ flags) {
  __shared__ int er[CH];
  __shared__ int ec[CH];
  __shared__ int ee[CH];
  __shared__ int hA[256];
  __shared__ int hB[256];
  const int tid = threadIdx.x, blk = blockIdx.x;
  hA[tid] = 0; hB[tid] = 0;
  __syncthreads();
  const int i64 = flags[1], f16 = flags[0];
  const int m0 = blk * CH;
  const int cnt = min(M - m0, CH);
  for (int i = tid; i < cnt; i += 256) {
    int m = m0 + i;
    int r, c;
    if (i64) {
      r = (int)((const long long*)hei)[m];
      c = (int)((const long long*)hei)[M + m];
    } else {
      r = ((const int*)hei)[m];
      c = ((const int*)hei)[M + m];
    }
    er[i] = r; ec[i] = c;
    ee[i] = __float_as_int(f16 ? bf2f(((const unsigned short*)ew)[m])
                                : ((const float*)ew)[m]);
    atomicAdd(&hA[c >> CW_SHIFT], 1);
    atomicAdd(&hB[r >> CW_SHIFT], 1);
  }
  __syncthreads();
  // reserve chunks: hA/hB become running slot cursors (global slot index)
  {
    int nA = (tid < nbE) ? hA[tid] : 0;
    int nB = (tid < nbN) ? hB[tid] : 0;
    __syncthreads();
    if (tid < nbE) hA[tid] = (tid << CAP_SHIFT) + (nA ? atomicAdd(gcurA + tid, nA) : 0);
    if (tid < nbN) hB[tid] = (tid << CAP_SHIFT) + (nB ? atomicAdd(gcurB + tid, nB) : 0);
  }
  __syncthreads();
  for (int i = tid; i < cnt; i += 256) {
    int r = er[i], c = ec[i], e = ee[i];
    int pA = atomicAdd(&hA[c >> CW_SHIFT], 1);
    i2 ea; ea[0] = r | ((c & (CW - 1)) << 20); ea[1] = e;
    SLOTA[pA] = ea;
    int pB = atomicAdd(&hB[r >> CW_SHIFT], 1);
    i2 eb; eb[0] = c | ((r & (CW - 1)) << 20); eb[1] = e;
    SLOTB[pB] = eb;
  }
}

// ---- scanB: 2 blocks; exclusive scan of per-bucket counts -> compact bases ----
__global__ __launch_bounds__(512) void scanB(const int* __restrict__ gcurA,
                                             const int* __restrict__ gcurB,
                                             int* __restrict__ bbaseA,
                                             int* __restrict__ bbaseB,
                                             int nbE, int nbN) {
  __shared__ int sc[512];
  const int tid = threadIdx.x;
  const int nb = blockIdx.x ? nbN : nbE;
  const int* src = blockIdx.x ? gcurB : gcurA;
  int* dst = blockIdx.x ? bbaseB : bbaseA;
  int v = (tid < nb) ? src[tid] : 0;
  sc[tid] = v;
  __syncthreads();
  for (int s = 1; s < 512; s <<= 1) {
    int t = (tid >= s) ? sc[tid - s] : 0;
    __syncthreads();
    sc[tid] += t;
    __syncthreads();
  }
  if (tid < nb) dst[tid] = sc[tid] - v;
  if (tid == 511) dst[nb] = sc[511];
}

// ---- finalize: per-bucket slots -> compact CSR entries + offsets + scales ----
__global__ __launch_bounds__(256) void finalize3(
    const i2* __restrict__ SLOTA, const int* __restrict__ bbaseA,
    i2* __restrict__ ENTA, int* __restrict__ offE, int E,
    const i2* __restrict__ SLOTB, const int* __restrict__ bbaseB,
    i2* __restrict__ ENTB, int* __restrict__ offN, int Nn,
    const float* __restrict__ WMf, float* __restrict__ SCE,
    float* __restrict__ ND, int nbE) {
  __shared__ int cnt[CW];
  __shared__ int sc[CW];
  __shared__ int cur[CW];
  __shared__ float fsum[CW];
  int b = blockIdx.x;
  const i2* SLOT; const int* bbase; i2* ENT; int* off;
  int nseg, modeB; float* outScale;
  if (b < nbE) {
    SLOT = SLOTA; bbase = bbaseA; ENT = ENTA; off = offE;
    nseg = E; modeB = 0; outScale = SCE;
  } else {
    b -= nbE;
    SLOT = SLOTB; bbase = bbaseB; ENT = ENTB; off = offN;
    nseg = Nn; modeB = 1; outScale = ND;
  }
  const int tid = threadIdx.x;
  const int obase = bbase[b];
  const int nent = bbase[b + 1] - obase;
  const int bs = b << CAP_SHIFT;           // slot base
  const int cb = b << CW_SHIFT;
  const int cw = min(CW, nseg - cb);
  cnt[tid] = 0; fsum[tid] = 0.f;
  __syncthreads();
  for (int k = tid; k < nent; k += 256)
    atomicAdd(&cnt[(SLOT[bs + k][0] >> 20) & (CW - 1)], 1);
  __syncthreads();
  sc[tid] = cnt[tid];
  __syncthreads();
  for (int s = 1; s < CW; s <<= 1) {
    int t = (tid >= s) ? sc[tid - s] : 0;
    __syncthreads();
    sc[tid] += t;
    __syncthreads();
  }
  {
    int start = obase + sc[tid] - cnt[tid];
    cur[tid] = start;
    if (tid < cw) off[cb + tid] = start;
  }
  if (tid == 0 && b == ((nseg + CW - 1) >> CW_SHIFT) - 1) off[nseg] = obase + nent;
  __syncthreads();
  for (int k = tid; k < nent; k += 256) {
    i2 p = SLOT[bs + k];
    int key = (p[0] >> 20) & (CW - 1);
    int src = p[0] & 0xFFFFF;
    int pos = atomicAdd(&cur[key], 1);
    i2 outp; outp[0] = src; outp[1] = p[1];
    ENT[pos] = outp;
    float add = modeB ? WMf[src] : __int_as_float(p[1]);
    atomicAdd(&fsum[key], add);
  }
  __syncthreads();
  if (tid < cw) {
    float s = fsum[tid] + 1e-8f;
    outScale[cb + tid] = modeB ? rsqrtf(s) : (WMf[cb + tid] / s);
  }
}

// ---- MFMA GEMM v3: LDS-staged weights + fully hoisted A loads ----
template<int KS>
__global__ __launch_bounds__(256) void gemm_mfma3(
    const void* __restrict__ Aptr, const unsigned short* __restrict__ Wt,
    const float* __restrict__ bias, unsigned short* __restrict__ out,
    int Nrows, const int* __restrict__ flags, int relu,
    const float* __restrict__ rowScale) {
  constexpr int K = KS * 32;
  constexpr int KC = K / 8;
  extern __shared__ unsigned short Bs[];
  const int tid = threadIdx.x;
  const int wv = tid >> 6, ln = tid & 63;
  const int lr = ln & 15;
  const int lk = (ln >> 4) << 3;
  const int rowBase = blockIdx.x * 128 + wv * 32;
  const int aF32 = flags ? (flags[0] ? 0 : 1) : 0;

  int ar[2];
#pragma unroll
  for (int t = 0; t < 2; ++t) {
    int r = rowBase + t * 16 + lr;
    ar[t] = (r < Nrows) ? r : (Nrows - 1);
  }

  s8b aR[2][KS];
  if (!aF32) {
#pragma unroll
    for (int t = 0; t < 2; ++t)
#pragma unroll
      for (int ks = 0; ks < KS; ++ks)
        aR[t][ks] = *reinterpret_cast<const s8b*>(
            (const unsigned short*)Aptr + (size_t)ar[t] * K + ks * 32 + lk);
  } else {
#pragma unroll
    for (int t = 0; t < 2; ++t)
#pragma unroll
      for (int ks = 0; ks < KS; ++ks) {
        const float* ap = (const float*)Aptr + (size_t)ar[t] * K + ks * 32 + lk;
        f4 u0 = *reinterpret_cast<const f4*>(ap);
        f4 u1 = *reinterpret_cast<const f4*>(ap + 4);
#pragma unroll
        for (int j = 0; j < 4; ++j) {
          aR[t][ks][j]     = (short)f2bf(u0[j]);
          aR[t][ks][4 + j] = (short)f2bf(u1[j]);
        }
      }
  }

#pragma unroll
  for (int it = 0; it < (128 * KC + 255) / 256; ++it) {
    int ch = it * 256 + tid;
    if (ch < 128 * KC) {
      int row = ch / KC, kc = (ch % KC) << 3;
      us8 v = *reinterpret_cast<const us8*>(Wt + (size_t)row * K + kc);
      int byte = ((row * K + kc) << 1) ^ ((row & 7) << 4);
      *reinterpret_cast<us8*>((char*)Bs + byte) = v;
    }
  }
  __syncthreads();

  f32x4 acc[2][8];
#pragma unroll
  for (int t = 0; t < 2; ++t)
#pragma unroll
    for (int n = 0; n < 8; ++n) acc[t][n] = (f32x4)0.f;

#pragma unroll
  for (int ks = 0; ks < KS; ++ks) {
#pragma unroll
    for (int n = 0; n < 8; ++n) {
      const int brow = n * 16 + lr;
      int byte = ((brow * K + ks * 32 + lk) << 1) ^ ((brow & 7) << 4);
      s8b b = *reinterpret_cast<const s8b*>((const char*)Bs + byte);
      acc[0][n] = __builtin_amdgcn_mfma_f32_16x16x32_bf16(aR[0][ks], b, acc[0][n], 0, 0, 0);
      acc[1][n] = __builtin_amdgcn_mfma_f32_16x16x32_bf16(aR[1][ks], b, acc[1][n], 0, 0, 0);
    }
  }

#pragma unroll
  for (int t = 0; t < 2; ++t) {
    const int orow0 = rowBase + t * 16 + ((ln >> 4) << 2);
#pragma unroll
    for (int n = 0; n < 8; ++n) {
      const int col = n * 16 + lr;
      const float bv = bias[col];
#pragma unroll
      for (int r = 0; r < 4; ++r) {
        int row = orow0 + r;
        if (row >= Nrows) continue;
        float s = acc[t][n][r] + bv;
        if (relu) s = fmaxf(s, 0.f);
        if (rowScale) s *= rowScale[row];
        out[(size_t)row * 128 + col] = f2bf(s);
      }
    }
  }
}

// ---- gather v5: 4 segments/wave, 16 lanes * us8 (16B) per row, 4-deep unroll ----
__global__ __launch_bounds__(256) void gather_edge3(
    const int* __restrict__ off, const i2* __restrict__ ENT,
    const float* __restrict__ sc_e, const unsigned short* __restrict__ X,
    unsigned short* __restrict__ out, int nseg) {
  int seg = blockIdx.x * 16 + (threadIdx.x >> 4);
  if (seg >= nseg) return;
  int d = (threadIdx.x & 15) << 3;
  int k0 = off[seg], k1 = off[seg + 1];
  float a0 = 0.f, a1 = 0.f, a2 = 0.f, a3 = 0.f, a4 = 0.f, a5 = 0.f, a6 = 0.f, a7 = 0.f;
  int k = k0;
  for (; k + 4 <= k1; k += 4) {
    i2 e0 = ENT[k], e1 = ENT[k + 1], e2 = ENT[k + 2], e3 = ENT[k + 3];
    us8 v0 = *reinterpret_cast<const us8*>(X + (size_t)e0[0] * 128 + d);
    us8 v1 = *reinterpret_cast<const us8*>(X + (size_t)e1[0] * 128 + d);
    us8 v2 = *reinterpret_cast<const us8*>(X + (size_t)e2[0] * 128 + d);
    us8 v3 = *reinterpret_cast<const us8*>(X + (size_t)e3[0] * 128 + d);
    float c0 = __int_as_float(e0[1]), c1 = __int_as_float(e1[1]);
    float c2 = __int_as_float(e2[1]), c3 = __int_as_float(e3[1]);
    a0 += c0 * bf2f(v0[0]); a1 += c0 * bf2f(v0[1]); a2 += c0 * bf2f(v0[2]); a3 += c0 * bf2f(v0[3]);
    a4 += c0 * bf2f(v0[4]); a5 += c0 * bf2f(v0[5]); a6 += c0 * bf2f(v0[6]); a7 += c0 * bf2f(v0[7]);
    a0 += c1 * bf2f(v1[0]); a1 += c1 * bf2f(v1[1]); a2 += c1 * bf2f(v1[2]); a3 += c1 * bf2f(v1[3]);
    a4 += c1 * bf2f(v1[4]); a5 += c1 * bf2f(v1[5]); a6 += c1 * bf2f(v1[6]); a7 += c1 * bf2f(v1[7]);
    a0 += c2 * bf2f(v2[0]); a1 += c2 * bf2f(v2[1]); a2 += c2 * bf2f(v2[2]); a3 += c2 * bf2f(v2[3]);
    a4 += c2 * bf2f(v2[4]); a5 += c2 * bf2f(v2[5]); a6 += c2 * bf2f(v2[6]); a7 += c2 * bf2f(v2[7]);
    a0 += c3 * bf2f(v3[0]); a1 += c3 * bf2f(v3[1]); a2 += c3 * bf2f(v3[2]); a3 += c3 * bf2f(v3[3]);
    a4 += c3 * bf2f(v3[4]); a5 += c3 * bf2f(v3[5]); a6 += c3 * bf2f(v3[6]); a7 += c3 * bf2f(v3[7]);
  }
  for (; k < k1; ++k) {
    i2 e = ENT[k];
    us8 v = *reinterpret_cast<const us8*>(X + (size_t)e[0] * 128 + d);
    float c = __int_as_float(e[1]);
    a0 += c * bf2f(v[0]); a1 += c * bf2f(v[1]); a2 += c * bf2f(v[2]); a3 += c * bf2f(v[3]);
    a4 += c * bf2f(v[4]); a5 += c * bf2f(v[5]); a6 += c * bf2f(v[6]); a7 += c * bf2f(v[7]);
  }
  float sc = sc_e[seg];
  us8 o;
  o[0] = f2bf(sc * a0); o[1] = f2bf(sc * a1); o[2] = f2bf(sc * a2); o[3] = f2bf(sc * a3);
  o[4] = f2bf(sc * a4); o[5] = f2bf(sc * a5); o[6] = f2bf(sc * a6); o[7] = f2bf(sc * a7);
  *reinterpret_cast<us8*>(out + (size_t)seg * 128 + d) = o;
}

__global__ __launch_bounds__(256) void gather_node3(
    const int* __restrict__ off, const i2* __restrict__ ENT,
    const float* __restrict__ nd, const unsigned short* __restrict__ HF,
    const unsigned short* __restrict__ H, void* __restrict__ out,
    int nseg, int outF32) {
  int seg = blockIdx.x * 16 + (threadIdx.x >> 4);
  if (seg >= nseg) return;
  int d = (threadIdx.x & 15) << 3;
  int k0 = off[seg], k1 = off[seg + 1];
  float a0 = 0.f, a1 = 0.f, a2 = 0.f, a3 = 0.f, a4 = 0.f, a5 = 0.f, a6 = 0.f, a7 = 0.f;
  int k = k0;
  for (; k + 4 <= k1; k += 4) {
    i2 e0 = ENT[k], e1 = ENT[k + 1], e2 = ENT[k + 2], e3 = ENT[k + 3];
    us8 v0 = *reinterpret_cast<const us8*>(HF + (size_t)e0[0] * 128 + d);
    us8 v1 = *reinterpret_cast<const us8*>(HF + (size_t)e1[0] * 128 + d);
    us8 v2 = *reinterpret_cast<const us8*>(HF + (size_t)e2[0] * 128 + d);
    us8 v3 = *reinterpret_cast<const us8*>(HF + (size_t)e3[0] * 128 + d);
    float c0 = __int_as_float(e0[1]), c1 = __int_as_float(e1[1]);
    float c2 = __int_as_float(e2[1]), c3 = __int_as_float(e3[1]);
    a0 += c0 * bf2f(v0[0]); a1 += c0 * bf2f(v0[1]); a2 += c0 * bf2f(v0[2]); a3 += c0 * bf2f(v0[3]);
    a4 += c0 * bf2f(v0[4]); a5 += c0 * bf2f(v0[5]); a6 += c0 * bf2f(v0[6]); a7 += c0 * bf2f(v0[7]);
    a0 += c1 * bf2f(v1[0]); a1 += c1 * bf2f(v1[1]); a2 += c1 * bf2f(v1[2]); a3 += c1 * bf2f(v1[3]);
    a4 += c1 * bf2f(v1[4]); a5 += c1 * bf2f(v1[5]); a6 += c1 * bf2f(v1[6]); a7 += c1 * bf2f(v1[7]);
    a0 += c2 * bf2f(v2[0]); a1 += c2 * bf2f(v2[1]); a2 += c2 * bf2f(v2[2]); a3 += c2 * bf2f(v2[3]);
    a4 += c2 * bf2f(v2[4]); a5 += c2 * bf2f(v2[5]); a6 += c2 * bf2f(v2[6]); a7 += c2 * bf2f(v2[7]);
    a0 += c3 * bf2f(v3[0]); a1 += c3 * bf2f(v3[1]); a2 += c3 * bf2f(v3[2]); a3 += c3 * bf2f(v3[3]);
    a4 += c3 * bf2f(v3[4]); a5 += c3 * bf2f(v3[5]); a6 += c3 * bf2f(v3[6]); a7 += c3 * bf2f(v3[7]);
  }
  for (; k < k1; ++k) {
    i2 e = ENT[k];
    us8 v = *reinterpret_cast<const us8*>(HF + (size_t)e[0] * 128 + d);
    float c = __int_as_float(e[1]);
    a0 += c * bf2f(v[0]); a1 += c * bf2f(v[1]); a2 += c * bf2f(v[2]); a3 += c * bf2f(v[3]);
    a4 += c * bf2f(v[4]); a5 += c * bf2f(v[5]); a6 += c * bf2f(v[6]); a7 += c * bf2f(v[7]);
  }
  float s = nd[seg];
  us8 h = *reinterpret_cast<const us8*>(H + (size_t)seg * 128 + d);
  float r0 = fmaxf(bf2f(h[0]) + s * a0, 0.f);
  float r1 = fmaxf(bf2f(h[1]) + s * a1, 0.f);
  float r2 = fmaxf(bf2f(h[2]) + s * a2, 0.f);
  float r3 = fmaxf(bf2f(h[3]) + s * a3, 0.f);
  float r4 = fmaxf(bf2f(h[4]) + s * a4, 0.f);
  float r5 = fmaxf(bf2f(h[5]) + s * a5, 0.f);
  float r6 = fmaxf(bf2f(h[6]) + s * a6, 0.f);
  float r7 = fmaxf(bf2f(h[7]) + s * a7, 0.f);
  if (outF32) {
    float* op = (float*)out + (size_t)seg * 128 + d;
    f4 o0, o1;
    o0[0] = r0; o0[1] = r1; o0[2] = r2; o0[3] = r3;
    o1[0] = r4; o1[1] = r5; o1[2] = r6; o1[3] = r7;
    *reinterpret_cast<f4*>(op) = o0;
    *reinterpret_cast<f4*>(op + 4) = o1;
  } else {
    us8 o;
    o[0] = f2bf(r0); o[1] = f2bf(r1); o[2] = f2bf(r2); o[3] = f2bf(r3);
    o[4] = f2bf(r4); o[5] = f2bf(r5); o[6] = f2bf(r6); o[7] = f2bf(r7);
    *reinterpret_cast<us8*>((unsigned short*)out + (size_t)seg * 128 + d) = o;
  }
}

extern "C" void kernel_launch(void* const* d_in, const int* in_sizes, int n_in,
                              void* d_out, int out_size, void* d_ws, size_t ws_size,
                              hipStream_t stream) {
  const void* x   = d_in[0];
  const void* hei = d_in[1];
  const void* wM  = d_in[2];
  const void* ew  = d_in[3];
  const void* fcw = d_in[4];
  const void* fcb = d_in[5];
  const void* cw  = d_in[6];
  const void* cb  = d_in[7];

  const int IN_DIM = 256, D = 128;
  const int N = in_sizes[0] / IN_DIM;
  const int M = in_sizes[1] / 2;
  const int E = in_sizes[2];
  const int L = in_sizes[6] / (D * D);

  const int nbE = (E + CW - 1) >> CW_SHIFT;
  const int nbN = (N + CW - 1) >> CW_SHIFT;
  const int nbT = nbE + nbN;
  const int nblk = (M + CH - 1) / CH;

  float* w = (float*)d_ws;
  size_t o = 0;
  auto alloc = [&](size_t n) { float* p = w + o; o += (n + 3) & ~(size_t)3; return p; };

  // R region hosts XT+HF (GEMM/gather phase). SLOT arrays are separate (ws is ~268MB).
  float* R = alloc((size_t)(N + E) * D / 2);
  unsigned short* XT = (unsigned short*)R;
  unsigned short* HF = XT + (size_t)N * D;

  i2* SLOTA = (i2*)alloc((size_t)nbE * CAP * 2);
  i2* SLOTB = (i2*)alloc((size_t)nbN * CAP * 2);
  unsigned short* H  = (unsigned short*)alloc((size_t)N * D / 2);
  i2*    ENTA = (i2*)alloc((size_t)M * 2);
  i2*    ENTB = (i2*)alloc((size_t)M * 2);
  int*   gcurA = (int*)alloc(nbE + 2);
  int*   gcurB = (int*)alloc(nbN + 2);
  int*   bbaseA = (int*)alloc(nbE + 2);
  int*   bbaseB = (int*)alloc(nbN + 2);
  float* ND   = alloc(N);
  float* SCE  = alloc(E);
  int*   offE = (int*)alloc(E + 1);
  int*   offN = (int*)alloc(N + 1);
  float* WMf  = alloc(E);
  unsigned short* FCWT = (unsigned short*)alloc((size_t)IN_DIM * D / 2);
  float* FCB  = alloc(D);
  unsigned short* CWT = (unsigned short*)alloc((size_t)L * D * D / 2);
  float* CBf  = alloc((size_t)L * D);
  int*   FLAGS = (int*)alloc(16);

  // detect also zeroes gcurA..gcurB (contiguous allocs: zero both via length)
  detect_kernel<<<1, 64, 0, stream>>>((const unsigned int*)x, (const unsigned int*)hei,
                                      FLAGS, gcurA, (int)(((nbE + 2 + 3) & ~3) + nbN + 2));

  {
    int ntot = E + IN_DIM * D + D + L * D * D + L * D;
    cvt_params<<<(ntot + 255) / 256, 256, 0, stream>>>(wM, fcw, fcb, cw, cb,
                                                       WMf, FCWT, FCB, CWT, CBf,
                                                       E, L, FLAGS);
  }

  fused_scatter<<<nblk, 256, 0, stream>>>(hei, ew, M, gcurA, gcurB,
                                          SLOTA, SLOTB, nbE, nbN, FLAGS);

  scanB<<<2, 512, 0, stream>>>(gcurA, gcurB, bbaseA, bbaseB, nbE, nbN);

  finalize3<<<nbT, 256, 0, stream>>>(SLOTA, bbaseA, ENTA, offE, E,
                                     SLOTB, bbaseB, ENTB, offN, N,
                                     WMf, SCE, ND, nbE);

  // h0 = relu(x @ fc_w + fc_b)
  gemm_mfma3<8><<<(N + 127) / 128, 256, 128 * 256 * 2, stream>>>(
      x, FCWT, FCB, H, N, FLAGS, 1, nullptr);

  int segBlkE = (E + 15) / 16, segBlkN = (N + 15) / 16;
  for (int l = 0; l < L; ++l) {
    // xt' = nd[r] * (h @ conv_w[l] + conv_b[l])
    gemm_mfma3<4><<<(N + 127) / 128, 256, 128 * 128 * 2, stream>>>(
        H, CWT + (size_t)l * D * D, CBf + (size_t)l * D, XT, N,
        (const int*)nullptr, 0, ND);
    gather_edge3<<<segBlkE, 256, 0, stream>>>(offE, ENTA, SCE, XT, HF, E);
    gather_node3<<<segBlkN, 256, 0, stream>>>(
        offN, ENTB, ND, HF, H,
        (l == L - 1) ? d_out : (void*)H, N, (l == L - 1) ? 1 : 0);
  }
}